// Round 16
// baseline (476.794 us; speedup 1.0000x reference)
//
#include <hip/hip_runtime.h>
#include <hip/hip_bf16.h>

typedef __bf16 bf16;
typedef bf16 bf16x8 __attribute__((ext_vector_type(8)));
typedef bf16 bf16x4 __attribute__((ext_vector_type(4)));
typedef float f32x4 __attribute__((ext_vector_type(4)));

#define MFMA16(a, b, c) __builtin_amdgcn_mfma_f32_16x16x32_bf16((a), (b), (c), 0, 0, 0)

__device__ __forceinline__ void gl_lds16(const void* g, void* l) {
    __builtin_amdgcn_global_load_lds((const __attribute__((address_space(1))) void*)g,
                                     (__attribute__((address_space(3))) void*)l, 16, 0, 0);
}

// ---------------------------------------------------------------------------
__global__ __launch_bounds__(256) void k_detect(const void* __restrict__ src, int* __restrict__ flag) {
    __shared__ int cnt;
    if (threadIdx.x == 0) cnt = 0;
    __syncthreads();
    const unsigned int* w = (const unsigned int*)src;
    int local = 0;
    for (int i = threadIdx.x; i < 4096; i += 256) {
        unsigned int e = (w[i] >> 7) & 0xFF;
        local += (e > 100 && e < 150) ? 1 : 0;
    }
    atomicAdd(&cnt, local);
    __syncthreads();
    if (threadIdx.x == 0) *flag = (cnt > 2048) ? 1 : 0;
}

struct BigSegs {
    const void* src[6];
    bf16* dst[6];
    int cum[7];
};
// copy only when inputs are f32 (flag==0); bf16 inputs consumed from d_in.
__global__ __launch_bounds__(256) void k_norm_big(const int* __restrict__ flag, BigSegs s) {
    if (*flag) return;
    int seg = 0;
#pragma unroll
    for (int t = 0; t < 5; t++) seg += (blockIdx.x >= s.cum[t + 1]) ? 1 : 0;
    int i = (blockIdx.x - s.cum[seg]) * 256 + threadIdx.x;
    const float* fs = (const float*)s.src[seg] + (size_t)i * 8;
    bf16x8 o;
#pragma unroll
    for (int j = 0; j < 8; j++) o[j] = (bf16)fs[j];
    ((bf16x8*)s.dst[seg])[i] = o;
}

struct SmallSegs {
    const void* src[13];
    bf16* dst[13];
    int n8[13];
};
__global__ __launch_bounds__(256) void k_norm_multi(const int* __restrict__ flag, SmallSegs s) {
    int seg = blockIdx.x;
    const void* sp = s.src[seg];
    bf16* dp = s.dst[seg];
    int n = s.n8[seg];
    int f = *flag;
    for (int i = threadIdx.x; i < n; i += 256) {
        if (f) {
            ((bf16x8*)dp)[i] = ((const bf16x8*)sp)[i];
        } else {
            const float* fs = (const float*)sp + (size_t)i * 8;
            bf16x8 o;
#pragma unroll
            for (int j = 0; j < 8; j++) o[j] = (bf16)fs[j];
            ((bf16x8*)dp)[i] = o;
        }
    }
}

// tgt(f32) -> bf16 t0b; no-op when inputs are bf16.
__global__ __launch_bounds__(256) void k_cvt(const int* __restrict__ flag, const void* __restrict__ in,
                                             bf16* __restrict__ outb) {
    if (*flag) return;
    size_t i = (size_t)blockIdx.x * 256 + threadIdx.x;
    f32x4 a = ((const f32x4*)in)[i * 2];
    f32x4 b = ((const f32x4*)in)[i * 2 + 1];
    bf16x8 v;
#pragma unroll
    for (int j = 0; j < 4; j++) { v[j] = (bf16)a[j]; v[4 + j] = (bf16)b[j]; }
    ((bf16x8*)outb)[i] = v;
}

// ---------------------------------------------------------------------------
// transpose+permute: sru_w (1024,8192) -> wT' (8192,1024) with row n'=h*4+j
__global__ __launch_bounds__(256) void k_transpose(const int* __restrict__ flag, const void* __restrict__ in,
                                                   bf16* __restrict__ out, int R, int C) {
    __shared__ __align__(16) bf16 t[64][72];
    int tid = threadIdx.x;
    int c0 = blockIdx.x * 64, r0 = blockIdx.y * 64;
#pragma unroll
    for (int i = 0; i < 2; i++) {
        int idx = tid + i * 256;
        int r = idx >> 3, ch = idx & 7;
        size_t base = (size_t)(r0 + r) * C + c0 + ch * 8;
        bf16x8 v;
        if (*flag) {
            v = *(const bf16x8*)((const bf16*)in + base);
        } else {
            const float* f = (const float*)in + base;
            f32x4 x = *(const f32x4*)f, y = *(const f32x4*)(f + 4);
#pragma unroll
            for (int j = 0; j < 4; j++) { v[j] = (bf16)x[j]; v[4 + j] = (bf16)y[j]; }
        }
        *(bf16x8*)&t[r][ch * 8] = v;
    }
    __syncthreads();
    int nbase = c0 & 2047, joff = c0 >> 11;
#pragma unroll
    for (int i = 0; i < 2; i++) {
        int idx = tid + i * 256;
        int cr = idx >> 3, ch = idx & 7;
        bf16x8 v;
#pragma unroll
        for (int j = 0; j < 8; j++) v[j] = t[ch * 8 + j][cr];
        int np = (nbase + cr) * 4 + joff;
        *(bf16x8*)(out + (size_t)np * R + r0 + ch * 8) = v;
    }
}

// ---------------------------------------------------------------------------
// V pre-transpose: in rows m=s*4+b, 64 cols -> Vt[b][n][s] ([4][1024][1024])
__global__ __launch_bounds__(256) void k_vtr(const bf16* __restrict__ in, int ldv, bf16* __restrict__ out) {
    int nt = blockIdx.x, st = blockIdx.y, b = blockIdx.z;
    __shared__ __align__(16) bf16 t[64][72];
    int tid = threadIdx.x;
#pragma unroll
    for (int i = 0; i < 2; i++) {
        int idx = tid + i * 256;
        int r = idx >> 3, ch = idx & 7;
        bf16x8 v = *(const bf16x8*)(in + (size_t)((st * 64 + r) * 4 + b) * ldv + nt * 64 + ch * 8);
        *(bf16x8*)&t[r][ch * 8] = v;
    }
    __syncthreads();
#pragma unroll
    for (int i = 0; i < 2; i++) {
        int idx = tid + i * 256;
        int dr = idx >> 3, ch = idx & 7;
        bf16x8 v;
#pragma unroll
        for (int j = 0; j < 8; j++) v[j] = t[ch * 8 + j][dr];
        *(bf16x8*)(out + (size_t)(b * 1024 + nt * 64 + dr) * 1024 + st * 64 + ch * 8) = v;
    }
}

// ---------------------------------------------------------------------------
// GEMM (bf16 A): C = A @ W^T (+bias)(*scale). BMx128 tile, BK=64, 4 waves.
// Aalt/Walt: raw d_in pointers selected when *flagp (bf16 inputs, zero-copy).
__device__ __forceinline__ int swzB(int r, int byteInRow) {
    return r * 128 + (byteInRow ^ ((r & 7) << 4));
}

template <int BM>
__global__ __launch_bounds__(256) void k_gemm(
    const int* __restrict__ flagp,
    const bf16* __restrict__ A, const bf16* __restrict__ Aalt, int lda,
    const bf16* __restrict__ W, const bf16* __restrict__ Walt, int ldw,
    const bf16* __restrict__ bias,
    float* __restrict__ Cf, bf16* __restrict__ Cb, int ldc,
    int K, int scale_end, float scale) {
    constexpr int MI = BM / 32;
    __shared__ __align__(16) char Asm[BM * 128];
    __shared__ __align__(16) char Bsm[128 * 128];
    if (*flagp) {
        if (Aalt) A = Aalt;
        if (Walt) W = Walt;
    }
    int tid = threadIdx.x, w = tid >> 6, l = tid & 63, lg = l >> 4, lm = l & 15;
    int wm = w >> 1, wn = w & 1;
    int m0 = blockIdx.y * BM, n0 = blockIdx.x * 128;

    f32x4 acc[MI][4] = {};

    for (int k0 = 0; k0 < K; k0 += 64) {
#pragma unroll
        for (int i = 0; i < BM / 32; i++) {
            int r = i * 32 + w * 8 + (l >> 3);
            int gs = (l & 7) ^ (r & 7);
            gl_lds16(A + (size_t)(m0 + r) * lda + k0 + gs * 8,
                     Asm + (i * 32 + w * 8) * 128);
        }
#pragma unroll
        for (int i = 0; i < 4; i++) {
            int r = i * 32 + w * 8 + (l >> 3);
            int gs = (l & 7) ^ (r & 7);
            gl_lds16(W + (size_t)(n0 + r) * ldw + k0 + gs * 8,
                     Bsm + (i * 32 + w * 8) * 128);
        }
        __syncthreads();
#pragma unroll
        for (int kh = 0; kh < 2; kh++) {
            bf16x8 af[MI], bfr[4];
#pragma unroll
            for (int i = 0; i < MI; i++)
                af[i] = *(const bf16x8*)(Asm + swzB(wm * (BM / 2) + i * 16 + lm, kh * 64 + lg * 16));
#pragma unroll
            for (int j = 0; j < 4; j++)
                bfr[j] = *(const bf16x8*)(Bsm + swzB(wn * 64 + j * 16 + lm, kh * 64 + lg * 16));
#pragma unroll
            for (int i = 0; i < MI; i++)
#pragma unroll
                for (int j = 0; j < 4; j++)
                    acc[i][j] = MFMA16(af[i], bfr[j], acc[i][j]);
        }
        __syncthreads();
    }
#pragma unroll
    for (int j = 0; j < 4; j++) {
        int col = n0 + wn * 64 + j * 16 + lm;
        float bv = bias ? (float)bias[col] : 0.f;
        float sc = (col < scale_end) ? scale : 1.f;
#pragma unroll
        for (int i = 0; i < MI; i++) {
            int row = m0 + wm * (BM / 2) + i * 16 + lg * 4;
#pragma unroll
            for (int r = 0; r < 4; r++) {
                float v = (acc[i][j][r] + bv) * sc;
                size_t idx = (size_t)(row + r) * ldc + col;
                if (Cf) Cf[idx] = v;
                if (Cb) Cb[idx] = (bf16)v;
            }
        }
    }
}

// ---------------------------------------------------------------------------
// SRU GEMM: 256x128 tile, BK=64, 8 waves (4M x 2N), 512 threads.
// Barriers amortized over 2x MFMA vs BM=128. USCAT epilogue stages one
// U2-buffer at a time in dead Asm; 256B fully-contiguous runs (no RMW).
__global__ __launch_bounds__(512) void k_gemm256u(
    const bf16* __restrict__ A, int lda,
    const bf16* __restrict__ W, int ldw,
    bf16* __restrict__ U2a, bf16* __restrict__ U2b) {
    __shared__ __align__(16) char Asm[256 * 128];  // 32KB
    __shared__ __align__(16) char Bsm[128 * 128];  // 16KB
    int tid = threadIdx.x, w = tid >> 6, l = tid & 63, lg = l >> 4, lm = l & 15;
    int wm = w >> 1, wn = w & 1;  // 4 x 2 waves
    int m0 = blockIdx.y * 256, n0 = blockIdx.x * 128;

    f32x4 acc[4][4] = {};

    for (int k0 = 0; k0 < 1024; k0 += 64) {
#pragma unroll
        for (int i = 0; i < 4; i++) {  // A: 256 rows, 8 waves x 8 rows per instr
            int r = i * 64 + w * 8 + (l >> 3);
            int gs = (l & 7) ^ (r & 7);
            gl_lds16(A + (size_t)(m0 + r) * lda + k0 + gs * 8,
                     Asm + (i * 64 + w * 8) * 128);
        }
#pragma unroll
        for (int i = 0; i < 2; i++) {  // B: 128 rows
            int r = i * 64 + w * 8 + (l >> 3);
            int gs = (l & 7) ^ (r & 7);
            gl_lds16(W + (size_t)(n0 + r) * ldw + k0 + gs * 8,
                     Bsm + (i * 64 + w * 8) * 128);
        }
        __syncthreads();
#pragma unroll
        for (int kh = 0; kh < 2; kh++) {
            bf16x8 af[4], bfr[4];
#pragma unroll
            for (int i = 0; i < 4; i++)
                af[i] = *(const bf16x8*)(Asm + swzB(wm * 64 + i * 16 + lm, kh * 64 + lg * 16));
#pragma unroll
            for (int j = 0; j < 4; j++)
                bfr[j] = *(const bf16x8*)(Bsm + swzB(wn * 64 + j * 16 + lm, kh * 64 + lg * 16));
#pragma unroll
            for (int i = 0; i < 4; i++)
#pragma unroll
                for (int j = 0; j < 4; j++)
                    acc[i][j] = MFMA16(af[i], bfr[j], acc[i][j]);
        }
        __syncthreads();
    }
    // USCAT epilogue. gate = lm&3 (j-independent) -> each lane belongs to one
    // buffer pass. Runs: [b:4][chl:32] x 256B (64 steps x 2 gates).
    bf16* ls = (bf16*)Asm;  // 32KB staging
    int gate = lm & 3;
    int g01 = gate & 1;
    int mybuf = gate >> 1;
#pragma unroll
    for (int buf = 0; buf < 2; buf++) {
        __syncthreads();  // ls free (k-loop or previous pass done)
        if (mybuf == buf) {
#pragma unroll
            for (int j = 0; j < 4; j++) {
                int chl = wn * 16 + j * 4 + (lm >> 2);  // 0..31
#pragma unroll
                for (int i = 0; i < 4; i++) {
                    int sl = wm * 16 + i * 4 + lg;      // 0..63
                    int boff = (sl * 2 + g01) * 2;
                    int swz = boff ^ ((chl & 7) << 4);
#pragma unroll
                    for (int r = 0; r < 4; r++)
                        *(bf16*)((char*)ls + (r * 32 + chl) * 256 + swz) = (bf16)acc[i][j][r];
                }
            }
        }
        __syncthreads();
        // write: 512 threads, 128 runs, 4 threads/run, 64B each
        int run = tid >> 2, part = tid & 3;
        int bb = run >> 5, chl = run & 31;
        bf16* dstb = (buf == 0) ? U2a : U2b;
        int ch = bb * 2048 + (n0 >> 2) + chl;
        size_t gb = (size_t)ch * 2048 + (size_t)(m0 >> 2) * 2;
        const char* src = (const char*)ls + (bb * 32 + chl) * 256;
#pragma unroll
        for (int k = 0; k < 4; k++) {
            int q = part * 4 + k;
            int pq = (q * 16) ^ ((chl & 7) << 4);
            *(bf16x8*)(dstb + gb + q * 8) = *(const bf16x8*)(src + pq);
        }
    }
}

// ---------------------------------------------------------------------------
// Flash attention (round-14 proven structure): QBLK=128, single K/V buffer,
// 2 barriers/kt, V pre-transposed, lazy defer-max, lane-partial lrun.
__device__ __forceinline__ int swz2(int row, int byteInRow) {
    return row * 128 + (byteInRow ^ ((row & 7) << 4));
}
__device__ __forceinline__ int swzP(int row, int byteInRow) {
    return row * 128 + (byteInRow ^ ((row & 3) << 4) ^ (((row >> 2) & 1) << 6));
}

__global__ __launch_bounds__(256) void k_attn(
    const bf16* __restrict__ Qp, const bf16* __restrict__ Kp, const bf16* __restrict__ Vt,
    int ldq, int ldk, bf16* __restrict__ Op) {
    int h = blockIdx.x & 15, b = blockIdx.x >> 4, qblk = blockIdx.y;
    int tid = threadIdx.x, w = tid >> 6, l = tid & 63, lg = l >> 4, lm = l & 15;
    int r0 = tid >> 3, ch = tid & 7;

    __shared__ __align__(16) char Ksm[64 * 128];
    __shared__ __align__(16) char Vsm[64 * 128];
    __shared__ __align__(16) char Psm[4][32 * 128];

    bf16x8 qf[2][2];
#pragma unroll
    for (int u = 0; u < 2; u++) {
        int qrow = qblk * 128 + w * 32 + u * 16 + lm;
#pragma unroll
        for (int kk = 0; kk < 2; kk++)
            qf[u][kk] = *(const bf16x8*)(Qp + (size_t)(qrow * 4 + b) * ldq + h * 64 + kk * 32 + lg * 8);
    }

    const bf16* vbase = Vt + (size_t)(b * 1024 + h * 64) * 1024;

    bf16x8 kreg[2], vreg[2];
#pragma unroll
    for (int p = 0; p < 2; p++) {
        int r = r0 + p * 32;
        kreg[p] = *(const bf16x8*)(Kp + (size_t)(r * 4 + b) * ldk + h * 64 + ch * 8);
        vreg[p] = *(const bf16x8*)(vbase + (size_t)r * 1024 + ch * 8);
    }

    f32x4 oa[2][4] = {};
    float mrun[2][4], lrun[2][4];
#pragma unroll
    for (int u = 0; u < 2; u++)
#pragma unroll
        for (int r = 0; r < 4; r++) { mrun[u][r] = -1e30f; lrun[u][r] = 0.f; }

    for (int kt = 0; kt < 16; kt++) {
        __syncthreads();
#pragma unroll
        for (int p = 0; p < 2; p++) {
            int r = r0 + p * 32;
            *(bf16x8*)(Ksm + swz2(r, ch * 16)) = kreg[p];
            *(bf16x8*)(Vsm + swz2(r, ch * 16)) = vreg[p];
        }
        if (kt < 15) {
#pragma unroll
            for (int p = 0; p < 2; p++) {
                int r = (kt + 1) * 64 + r0 + p * 32;
                kreg[p] = *(const bf16x8*)(Kp + (size_t)(r * 4 + b) * ldk + h * 64 + ch * 8);
                vreg[p] = *(const bf16x8*)(vbase + (size_t)(r0 + p * 32) * 1024 + (kt + 1) * 64 + ch * 8);
            }
        }
        __syncthreads();

        f32x4 sc[2][4] = {};
#pragma unroll
        for (int kk = 0; kk < 2; kk++)
#pragma unroll
            for (int jt = 0; jt < 4; jt++) {
                bf16x8 bk = *(const bf16x8*)(Ksm + swz2(jt * 16 + lm, kk * 64 + lg * 16));
#pragma unroll
                for (int u = 0; u < 2; u++)
                    sc[u][jt] = MFMA16(qf[u][kk], bk, sc[u][jt]);
            }

        float lmax[2][4];
        bool grow = false;
#pragma unroll
        for (int u = 0; u < 2; u++)
#pragma unroll
            for (int r = 0; r < 4; r++) {
                lmax[u][r] = fmaxf(fmaxf(sc[u][0][r], sc[u][1][r]), fmaxf(sc[u][2][r], sc[u][3][r]));
                grow = grow || (lmax[u][r] > mrun[u][r] + 8.f);
            }
        if (__any(grow)) {
#pragma unroll
            for (int u = 0; u < 2; u++)
#pragma unroll
                for (int r = 0; r < 4; r++) {
                    float m = lmax[u][r];
#pragma unroll
                    for (int d = 1; d < 16; d <<= 1) m = fmaxf(m, __shfl_xor(m, d));
                    float mn = fmaxf(mrun[u][r], m);
                    float al = __expf(mrun[u][r] - mn);
                    mrun[u][r] = mn;
                    lrun[u][r] *= al;
#pragma unroll
                    for (int ot = 0; ot < 4; ot++) oa[u][ot][r] *= al;
                }
        }
#pragma unroll
        for (int u = 0; u < 2; u++)
#pragma unroll
            for (int jt = 0; jt < 4; jt++)
#pragma unroll
                for (int r = 0; r < 4; r++) {
                    float p = __expf(sc[u][jt][r] - mrun[u][r]);
                    sc[u][jt][r] = p;
                    lrun[u][r] += p;
                }
#pragma unroll
        for (int u = 0; u < 2; u++)
#pragma unroll
            for (int jt = 0; jt < 4; jt++)
#pragma unroll
                for (int r = 0; r < 4; r++)
                    *(bf16*)(Psm[w] + swzP(u * 16 + lg * 4 + r, (jt * 16 + lm) * 2)) = (bf16)sc[u][jt][r];
        asm volatile("s_waitcnt lgkmcnt(0)" ::: "memory");
        __builtin_amdgcn_sched_barrier(0);
#pragma unroll
        for (int kk = 0; kk < 2; kk++) {
            bf16x8 pa[2];
#pragma unroll
            for (int u = 0; u < 2; u++)
                pa[u] = *(const bf16x8*)(Psm[w] + swzP(u * 16 + lm, kk * 64 + lg * 16));
#pragma unroll
            for (int ot = 0; ot < 4; ot++) {
                bf16x8 bv = *(const bf16x8*)(Vsm + swz2(ot * 16 + lm, kk * 64 + lg * 16));
#pragma unroll
                for (int u = 0; u < 2; u++)
                    oa[u][ot] = MFMA16(pa[u], bv, oa[u][ot]);
            }
        }
    }
#pragma unroll
    for (int u = 0; u < 2; u++)
#pragma unroll
        for (int r = 0; r < 4; r++) {
#pragma unroll
            for (int d = 1; d < 16; d <<= 1) lrun[u][r] += __shfl_xor(lrun[u][r], d);
            float inv = 1.f / lrun[u][r];
            int srow = qblk * 128 + w * 32 + u * 16 + lg * 4 + r;
#pragma unroll
            for (int ot = 0; ot < 4; ot++) {
                int col = h * 64 + ot * 16 + lm;
                Op[(size_t)(srow * 4 + b) * 1024 + col] = (bf16)(oa[u][ot][r] * inv);
            }
        }
}

// ---------------------------------------------------------------------------
// residual-add + LayerNorm over D=1024 (f32 math). Xalt when *flagp.
template <typename XT>
__global__ __launch_bounds__(256) void k_addln(
    const int* __restrict__ flagp,
    const XT* __restrict__ X, const XT* __restrict__ Xalt, const float* __restrict__ Yd,
    const bf16* __restrict__ g, const bf16* __restrict__ bb,
    float* __restrict__ outF, bf16* __restrict__ outB) {
    if (*flagp && Xalt) X = Xalt;
    int row = blockIdx.x * 4 + (threadIdx.x >> 6);
    int l = threadIdx.x & 63;
    const XT* xr = X + (size_t)row * 1024;
    const float* yr = Yd + (size_t)row * 1024;
    float v[16];
    float s = 0.f, s2 = 0.f;
#pragma unroll
    for (int q = 0; q < 4; q++) {
        float xa[4];
        if constexpr (sizeof(XT) == 4) {
            f32x4 a = *(const f32x4*)(xr + l * 4 + q * 256);
#pragma unroll
            for (int j = 0; j < 4; j++) xa[j] = a[j];
        } else {
            bf16x4 a = *(const bf16x4*)(xr + l * 4 + q * 256);
#pragma unroll
            for (int j = 0; j < 4; j++) xa[j] = (float)a[j];
        }
        f32x4 c = *(const f32x4*)(yr + l * 4 + q * 256);
#pragma unroll
        for (int j = 0; j < 4; j++) {
            float t = xa[j] + c[j];
            v[q * 4 + j] = t;
            s += t;
            s2 += t * t;
        }
    }
#pragma unroll
    for (int d = 1; d < 64; d <<= 1) { s += __shfl_xor(s, d); s2 += __shfl_xor(s2, d); }
    float mu = s * (1.f / 1024.f);
    float var = s2 * (1.f / 1024.f) - mu * mu;
    float rstd = rsqrtf(var + 1e-5f);
#pragma unroll
    for (int q = 0; q < 4; q++)
#pragma unroll
        for (int j = 0; j < 4; j++) {
            int col = l * 4 + q * 256 + j;
            float y = (v[q * 4 + j] - mu) * rstd * (float)g[col] + (float)bb[col];
            if (outF) outF[(size_t)row * 1024 + col] = y;
            if (outB) outB[(size_t)row * 1024 + col] = (bf16)y;
        }
}

// ---------------------------------------------------------------------------
// SRU segmented scan: 8 segments of 128 steps (affine maps), 2 phases.
__global__ __launch_bounds__(64) void k_sru_ab(
    const bf16* __restrict__ U2a, const bf16* __restrict__ v2, const bf16* __restrict__ b2,
    float* __restrict__ AB) {
    int ch = blockIdx.x * 64 + threadIdx.x;  // 0..8191
    int g = blockIdx.y;                      // 0..7
    int hh = ch & 2047;
    float vf = (float)v2[hh], bfv = (float)b2[hh];
    const bf16x8* u = (const bf16x8*)(U2a + (size_t)ch * 2048 + g * 256);
    float A = 1.f, c = 0.f;
    bf16x8 q[4];
#pragma unroll
    for (int i = 0; i < 4; i++) q[i] = u[i];
    for (int it = 0; it < 8; it++) {
#pragma unroll
        for (int j = 0; j < 4; j++) {
            int cidx = it * 4 + j;
            bf16x8 v = q[j];
            if (cidx + 4 < 32) q[j] = u[cidx + 4];
#pragma unroll
            for (int t = 0; t < 4; t++) {
                float xc = (float)v[t * 2], fp = (float)v[t * 2 + 1];
                float f = 1.f / (1.f + __expf(-(fp + vf * c + bfv)));
                A *= f;
                c = f * c + (1.f - f) * xc;
            }
        }
    }
    AB[(size_t)(g * 8192 + ch) * 2] = A;
    AB[(size_t)(g * 8192 + ch) * 2 + 1] = c;
}

__global__ __launch_bounds__(64) void k_sru_h(
    const bf16* __restrict__ U2a, const bf16* __restrict__ U2b,
    const bf16* __restrict__ v2, const bf16* __restrict__ b2,
    const float* __restrict__ AB, bf16* __restrict__ Hb) {
    int ch = blockIdx.x * 64 + threadIdx.x;
    int g = blockIdx.y;
    int b = ch >> 11, hh = ch & 2047;
    float vf = (float)v2[hh], vr = (float)v2[2048 + hh];
    float bfv = (float)b2[hh], brv = (float)b2[2048 + hh];
    float c = 0.f;
    for (int s = 0; s < g; s++) {  // wave-uniform bound
        float As = AB[(size_t)(s * 8192 + ch) * 2];
        float Bs = AB[(size_t)(s * 8192 + ch) * 2 + 1];
        c = As * c + Bs;
    }
    const bf16x8* ua = (const bf16x8*)(U2a + (size_t)ch * 2048 + g * 256);
    const bf16x8* ub = (const bf16x8*)(U2b + (size_t)ch * 2048 + g * 256);
    bf16* ho = Hb + ((size_t)(g * 128) * 4 + b) * 2048 + hh;
    bf16x8 qa[4], qb[4];
#pragma unroll
    for (int i = 0; i < 4; i++) { qa[i] = ua[i]; qb[i] = ub[i]; }
    for (int it = 0; it < 8; it++) {
#pragma unroll
        for (int j = 0; j < 4; j++) {
            int cidx = it * 4 + j;
            bf16x8 va = qa[j], vb = qb[j];
            if (cidx + 4 < 32) { qa[j] = ua[cidx + 4]; qb[j] = ub[cidx + 4]; }
#pragma unroll
            for (int t = 0; t < 4; t++) {
                float xc = (float)va[t * 2], fp = (float)va[t * 2 + 1];
                float rp = (float)vb[t * 2], xh = (float)vb[t * 2 + 1];
                float f = 1.f / (1.f + __expf(-(fp + vf * c + bfv)));
                float r = 1.f / (1.f + __expf(-(rp + vr * c + brv)));
                c = f * c + (1.f - f) * xc;
                float hv = r * c + (1.f - r) * xh;
                ho[(size_t)(cidx * 4 + t) * 8192] = (bf16)hv;
            }
        }
    }
}

// ---------------------------------------------------------------------------
extern "C" void kernel_launch(void* const* d_in, const int* in_sizes, int n_in,
                              void* d_out, int out_size, void* d_ws, size_t ws_size,
                              hipStream_t stream) {
    const size_t MB = 1u << 20;
    char* ws = (char*)d_ws;

    bf16* memB    = (bf16*)(ws + 0);
    bf16* sawinB  = (bf16*)(ws + 8 * MB);
    bf16* sawoutB = (bf16*)(ws + 14 * MB);
    bf16* cawinB  = (bf16*)(ws + 16 * MB);
    bf16* cawoutB = (bf16*)(ws + 22 * MB);
    bf16* lin2wB  = (bf16*)(ws + 24 * MB);
    char* S0 = ws + 28 * MB;
    bf16* sabinB  = (bf16*)(S0 + 0 * 8192);
    bf16* cabinB  = (bf16*)(S0 + 1 * 8192);
    bf16* saboutB = (bf16*)(S0 + 2 * 8192);
    bf16* caboutB = (bf16*)(S0 + 3 * 8192);
    bf16* lin2bB  = (bf16*)(S0 + 4 * 8192);
    bf16* sruvB   = (bf16*)(S0 + 5 * 8192);
    bf16* srubB   = (bf16*)(S0 + 6 * 8192);
    bf16* ln1gB   = (bf16*)(S0 + 7 * 8192);
    bf16* ln1bB   = (bf16*)(S0 + 8 * 8192);
    bf16* ln2gB   = (bf16*)(S0 + 9 * 8192);
    bf16* ln2bB   = (bf16*)(S0 + 10 * 8192);
    bf16* ln3gB   = (bf16*)(S0 + 11 * 8192);
    bf16* ln3bB   = (bf16*)(S0 + 12 * 8192);
    int*  flag    = (int*)(S0 + 13 * 8192);
    float* AB     = (float*)(S0 + 128 * 1024);  // 512 KB within the 1 MB region

    char* P = ws + 29 * MB;
    bf16*  t0b  = (bf16*)(P + 0);         // f32-input path only
    bf16*  qkv  = (bf16*)(P + 16 * MB);
    bf16*  qca  = qkv;
    bf16*  kvca = (bf16*)(P + 24 * MB);
    bf16*  obuf = (bf16*)(P + 40 * MB);
    bf16*  Vt   = (bf16*)(P + 56 * MB);
    float* tmp  = (float*)(P + 64 * MB);
    bf16*  t1   = (bf16*)(P + 80 * MB);
    bf16*  t2   = (bf16*)(ws + 0);        // overlays dead memB
    bf16*  wT   = (bf16*)(P + 0);         // overlays dead t0b (after ln1)
    bf16*  U2a  = (bf16*)(P + 16 * MB);   // 32MB
    bf16*  U2b  = (bf16*)(P + 48 * MB);   // 32MB
    bf16*  hb   = (bf16*)(P + 80 * MB);   // overlays dead t1
    float* tmp2 = (float*)(P + 16 * MB);  // U2a dead after scan

    const bf16* tgtA   = (const bf16*)d_in[0];
    const bf16* memA   = (const bf16*)d_in[1];
    const bf16* sawinA = (const bf16*)d_in[2];
    const bf16* sawoutA= (const bf16*)d_in[4];
    const bf16* cawinA = (const bf16*)d_in[6];
    const bf16* cawoutA= (const bf16*)d_in[8];
    const bf16* lin2wA = (const bf16*)d_in[13];

    k_detect<<<1, 256, 0, stream>>>(d_in[0], flag);
    BigSegs bg;
    {
        const void* bsrc[6] = {d_in[1], d_in[2], d_in[4], d_in[6], d_in[8], d_in[13]};
        bf16* bdst[6] = {memB, sawinB, sawoutB, cawinB, cawoutB, lin2wB};
        const int cum[7] = {0, 2048, 3584, 4096, 5632, 6144, 7168};
        for (int i = 0; i < 6; i++) { bg.src[i] = bsrc[i]; bg.dst[i] = bdst[i]; }
        for (int i = 0; i < 7; i++) bg.cum[i] = cum[i];
    }
    k_norm_big<<<7168, 256, 0, stream>>>(flag, bg);
    SmallSegs sg;
    const int srcIdx[13] = {3, 7, 5, 9, 14, 11, 12, 15, 16, 17, 18, 19, 20};
    bf16* dsts[13] = {sabinB, cabinB, saboutB, caboutB, lin2bB, sruvB, srubB,
                      ln1gB, ln1bB, ln2gB, ln2bB, ln3gB, ln3bB};
    const int n8s[13] = {384, 384, 128, 128, 128, 512, 512, 128, 128, 128, 128, 128, 128};
    for (int i = 0; i < 13; i++) { sg.src[i] = d_in[srcIdx[i]]; sg.dst[i] = dsts[i]; sg.n8[i] = n8s[i]; }
    k_norm_multi<<<13, 256, 0, stream>>>(flag, sg);

    k_cvt<<<2048, 256, 0, stream>>>(flag, d_in[0], t0b);

    // ---- self attention ----
    k_gemm<128><<<dim3(24, 32), 256, 0, stream>>>(flag, t0b, tgtA, 1024, sawinB, sawinA, 1024,
                                                  sabinB, nullptr, qkv, 3072, 1024, 1024, 0.125f);
    k_vtr<<<dim3(16, 16, 4), 256, 0, stream>>>(qkv + 2048, 3072, Vt);
    k_attn<<<dim3(64, 8), 256, 0, stream>>>(qkv, qkv + 1024, Vt, 3072, 3072, obuf);
    k_gemm<64><<<dim3(8, 64), 256, 0, stream>>>(flag, obuf, nullptr, 1024, sawoutB, sawoutA, 1024,
                                                saboutB, tmp, nullptr, 1024, 1024, 0, 1.f);
    k_addln<bf16><<<1024, 256, 0, stream>>>(flag, t0b, tgtA, tmp, ln1gB, ln1bB, nullptr, t1);

    // ---- cross attention ----
    k_gemm<64><<<dim3(8, 64), 256, 0, stream>>>(flag, t1, nullptr, 1024, cawinB, cawinA, 1024,
                                                cabinB, nullptr, qca, 1024, 1024, 1024, 0.125f);
    k_gemm<128><<<dim3(16, 32), 256, 0, stream>>>(flag, memB, memA, 1024,
                                                  cawinB + (size_t)1024 * 1024,
                                                  cawinA + (size_t)1024 * 1024, 1024,
                                                  cabinB + 1024, nullptr, kvca, 2048, 1024, 0, 1.f);
    k_vtr<<<dim3(16, 16, 4), 256, 0, stream>>>(kvca + 1024, 2048, Vt);
    k_attn<<<dim3(64, 8), 256, 0, stream>>>(qca, kvca, Vt, 1024, 2048, obuf);
    k_gemm<64><<<dim3(8, 64), 256, 0, stream>>>(flag, obuf, nullptr, 1024, cawoutB, cawoutA, 1024,
                                                caboutB, tmp, nullptr, 1024, 1024, 0, 1.f);
    k_addln<bf16><<<1024, 256, 0, stream>>>(flag, t1, nullptr, tmp, ln2gB, ln2bB, nullptr, t2);

    // ---- SRU ----
    k_transpose<<<dim3(128, 16), 256, 0, stream>>>(flag, d_in[10], wT, 1024, 8192);
    k_gemm256u<<<dim3(64, 16), 512, 0, stream>>>(t2, 1024, wT, 1024, U2a, U2b);
    k_sru_ab<<<dim3(128, 8), 64, 0, stream>>>(U2a, sruvB, srubB, AB);
    k_sru_h<<<dim3(128, 8), 64, 0, stream>>>(U2a, U2b, sruvB, srubB, AB, hb);
    k_gemm<64><<<dim3(8, 64), 256, 0, stream>>>(flag, hb, nullptr, 2048, lin2wB, lin2wA, 2048,
                                                lin2bB, tmp2, nullptr, 1024, 2048, 0, 1.f);
    k_addln<bf16><<<1024, 256, 0, stream>>>(flag, t2, nullptr, tmp2, ln3gB, ln3bB, (float*)d_out, nullptr);
}

// Round 17
// 457.772 us; speedup vs baseline: 1.0416x; 1.0416x over previous
//
#include <hip/hip_runtime.h>
#include <hip/hip_bf16.h>

typedef __bf16 bf16;
typedef bf16 bf16x8 __attribute__((ext_vector_type(8)));
typedef bf16 bf16x4 __attribute__((ext_vector_type(4)));
typedef float f32x4 __attribute__((ext_vector_type(4)));

#define MFMA16(a, b, c) __builtin_amdgcn_mfma_f32_16x16x32_bf16((a), (b), (c), 0, 0, 0)

__device__ __forceinline__ void gl_lds16(const void* g, void* l) {
    __builtin_amdgcn_global_load_lds((const __attribute__((address_space(1))) void*)g,
                                     (__attribute__((address_space(3))) void*)l, 16, 0, 0);
}

// ---------------------------------------------------------------------------
__global__ __launch_bounds__(256) void k_detect(const void* __restrict__ src, int* __restrict__ flag) {
    __shared__ int cnt;
    if (threadIdx.x == 0) cnt = 0;
    __syncthreads();
    const unsigned int* w = (const unsigned int*)src;
    int local = 0;
    for (int i = threadIdx.x; i < 4096; i += 256) {
        unsigned int e = (w[i] >> 7) & 0xFF;
        local += (e > 100 && e < 150) ? 1 : 0;
    }
    atomicAdd(&cnt, local);
    __syncthreads();
    if (threadIdx.x == 0) *flag = (cnt > 2048) ? 1 : 0;
}

struct BigSegs {
    const void* src[6];
    bf16* dst[6];
    int cum[7];
};
// copy only when inputs are f32 (flag==0); bf16 inputs consumed from d_in.
__global__ __launch_bounds__(256) void k_norm_big(const int* __restrict__ flag, BigSegs s) {
    if (*flag) return;
    int seg = 0;
#pragma unroll
    for (int t = 0; t < 5; t++) seg += (blockIdx.x >= s.cum[t + 1]) ? 1 : 0;
    int i = (blockIdx.x - s.cum[seg]) * 256 + threadIdx.x;
    const float* fs = (const float*)s.src[seg] + (size_t)i * 8;
    bf16x8 o;
#pragma unroll
    for (int j = 0; j < 8; j++) o[j] = (bf16)fs[j];
    ((bf16x8*)s.dst[seg])[i] = o;
}

struct SmallSegs {
    const void* src[13];
    bf16* dst[13];
    int n8[13];
};
__global__ __launch_bounds__(256) void k_norm_multi(const int* __restrict__ flag, SmallSegs s) {
    int seg = blockIdx.x;
    const void* sp = s.src[seg];
    bf16* dp = s.dst[seg];
    int n = s.n8[seg];
    int f = *flag;
    for (int i = threadIdx.x; i < n; i += 256) {
        if (f) {
            ((bf16x8*)dp)[i] = ((const bf16x8*)sp)[i];
        } else {
            const float* fs = (const float*)sp + (size_t)i * 8;
            bf16x8 o;
#pragma unroll
            for (int j = 0; j < 8; j++) o[j] = (bf16)fs[j];
            ((bf16x8*)dp)[i] = o;
        }
    }
}

// tgt(f32) -> bf16 t0b; no-op when inputs are bf16.
__global__ __launch_bounds__(256) void k_cvt(const int* __restrict__ flag, const void* __restrict__ in,
                                             bf16* __restrict__ outb) {
    if (*flag) return;
    size_t i = (size_t)blockIdx.x * 256 + threadIdx.x;
    f32x4 a = ((const f32x4*)in)[i * 2];
    f32x4 b = ((const f32x4*)in)[i * 2 + 1];
    bf16x8 v;
#pragma unroll
    for (int j = 0; j < 4; j++) { v[j] = (bf16)a[j]; v[4 + j] = (bf16)b[j]; }
    ((bf16x8*)outb)[i] = v;
}

// ---------------------------------------------------------------------------
// transpose+permute: sru_w (1024,8192) -> wT' (8192,1024) with row n'=h*4+j
__global__ __launch_bounds__(256) void k_transpose(const int* __restrict__ flag, const void* __restrict__ in,
                                                   bf16* __restrict__ out, int R, int C) {
    __shared__ __align__(16) bf16 t[64][72];
    int tid = threadIdx.x;
    int c0 = blockIdx.x * 64, r0 = blockIdx.y * 64;
#pragma unroll
    for (int i = 0; i < 2; i++) {
        int idx = tid + i * 256;
        int r = idx >> 3, ch = idx & 7;
        size_t base = (size_t)(r0 + r) * C + c0 + ch * 8;
        bf16x8 v;
        if (*flag) {
            v = *(const bf16x8*)((const bf16*)in + base);
        } else {
            const float* f = (const float*)in + base;
            f32x4 x = *(const f32x4*)f, y = *(const f32x4*)(f + 4);
#pragma unroll
            for (int j = 0; j < 4; j++) { v[j] = (bf16)x[j]; v[4 + j] = (bf16)y[j]; }
        }
        *(bf16x8*)&t[r][ch * 8] = v;
    }
    __syncthreads();
    int nbase = c0 & 2047, joff = c0 >> 11;
#pragma unroll
    for (int i = 0; i < 2; i++) {
        int idx = tid + i * 256;
        int cr = idx >> 3, ch = idx & 7;
        bf16x8 v;
#pragma unroll
        for (int j = 0; j < 8; j++) v[j] = t[ch * 8 + j][cr];
        int np = (nbase + cr) * 4 + joff;
        *(bf16x8*)(out + (size_t)np * R + r0 + ch * 8) = v;
    }
}

// ---------------------------------------------------------------------------
// V pre-transpose: in rows m=s*4+b, 64 cols -> Vt[b][n][s] ([4][1024][1024])
__global__ __launch_bounds__(256) void k_vtr(const bf16* __restrict__ in, int ldv, bf16* __restrict__ out) {
    int nt = blockIdx.x, st = blockIdx.y, b = blockIdx.z;
    __shared__ __align__(16) bf16 t[64][72];
    int tid = threadIdx.x;
#pragma unroll
    for (int i = 0; i < 2; i++) {
        int idx = tid + i * 256;
        int r = idx >> 3, ch = idx & 7;
        bf16x8 v = *(const bf16x8*)(in + (size_t)((st * 64 + r) * 4 + b) * ldv + nt * 64 + ch * 8);
        *(bf16x8*)&t[r][ch * 8] = v;
    }
    __syncthreads();
#pragma unroll
    for (int i = 0; i < 2; i++) {
        int idx = tid + i * 256;
        int dr = idx >> 3, ch = idx & 7;
        bf16x8 v;
#pragma unroll
        for (int j = 0; j < 8; j++) v[j] = t[ch * 8 + j][dr];
        *(bf16x8*)(out + (size_t)(b * 1024 + nt * 64 + dr) * 1024 + st * 64 + ch * 8) = v;
    }
}

// ---------------------------------------------------------------------------
// GEMM (bf16 A): C = A @ W^T (+bias)(*scale). BMx128 tile, BK=64, 4 waves.
// Aalt/Walt: raw d_in pointers selected when *flagp (bf16 inputs, zero-copy).
// USCAT epilogue: LDS-staged 128B-contiguous runs into U2a/U2b (proven 94.8us).
__device__ __forceinline__ int swzB(int r, int byteInRow) {
    return r * 128 + (byteInRow ^ ((r & 7) << 4));
}

template <int BM, bool USCAT>
__global__ __launch_bounds__(256) void k_gemm(
    const int* __restrict__ flagp,
    const bf16* __restrict__ A, const bf16* __restrict__ Aalt, int lda,
    const bf16* __restrict__ W, const bf16* __restrict__ Walt, int ldw,
    const bf16* __restrict__ bias,
    float* __restrict__ Cf, bf16* __restrict__ Cb, int ldc,
    int K, int scale_end, float scale) {
    constexpr int MI = BM / 32;
    __shared__ __align__(16) char Asm[BM * 128];
    __shared__ __align__(16) char Bsm[128 * 128];
    if (*flagp) {
        if (Aalt) A = Aalt;
        if (Walt) W = Walt;
    }
    int tid = threadIdx.x, w = tid >> 6, l = tid & 63, lg = l >> 4, lm = l & 15;
    int wm = w >> 1, wn = w & 1;
    int m0 = blockIdx.y * BM, n0 = blockIdx.x * 128;

    f32x4 acc[MI][4] = {};

    for (int k0 = 0; k0 < K; k0 += 64) {
#pragma unroll
        for (int i = 0; i < BM / 32; i++) {
            int r = i * 32 + w * 8 + (l >> 3);
            int gs = (l & 7) ^ (r & 7);
            gl_lds16(A + (size_t)(m0 + r) * lda + k0 + gs * 8,
                     Asm + (i * 32 + w * 8) * 128);
        }
#pragma unroll
        for (int i = 0; i < 4; i++) {
            int r = i * 32 + w * 8 + (l >> 3);
            int gs = (l & 7) ^ (r & 7);
            gl_lds16(W + (size_t)(n0 + r) * ldw + k0 + gs * 8,
                     Bsm + (i * 32 + w * 8) * 128);
        }
        __syncthreads();
#pragma unroll
        for (int kh = 0; kh < 2; kh++) {
            bf16x8 af[MI], bfr[4];
#pragma unroll
            for (int i = 0; i < MI; i++)
                af[i] = *(const bf16x8*)(Asm + swzB(wm * (BM / 2) + i * 16 + lm, kh * 64 + lg * 16));
#pragma unroll
            for (int j = 0; j < 4; j++)
                bfr[j] = *(const bf16x8*)(Bsm + swzB(wn * 64 + j * 16 + lm, kh * 64 + lg * 16));
#pragma unroll
            for (int i = 0; i < MI; i++)
#pragma unroll
                for (int j = 0; j < 4; j++)
                    acc[i][j] = MFMA16(af[i], bfr[j], acc[i][j]);
        }
        __syncthreads();
    }
    if constexpr (USCAT) {
        bf16* lsA = (bf16*)Asm;  // 16 KB (BM=128)
        bf16* lsB = (bf16*)Bsm;  // 16 KB
#pragma unroll
        for (int j = 0; j < 4; j++) {
            int cl = wn * 16 + j * 4 + (lm >> 2);
            int g = lm & 3;
            bf16* ls = (g < 2) ? lsA : lsB;
            int g01 = g & 1;
#pragma unroll
            for (int i = 0; i < MI; i++) {
                int slb = wm * 16 + i * 4 + lg;
                int boff = (slb * 2 + g01) * 2;
                int swz = boff ^ ((cl & 7) << 4);
#pragma unroll
                for (int r = 0; r < 4; r++) {
                    float v = acc[i][j][r];
                    *(bf16*)((char*)ls + (r * 32 + cl) * 128 + swz) = (bf16)v;
                }
            }
        }
        __syncthreads();
        int buf = tid >> 7, bb = (tid >> 5) & 3, cl = tid & 31;
        const char* ls = (buf == 0) ? (const char*)lsA : (const char*)lsB;
        bf16* dstbase = (buf == 0) ? Cb : (bf16*)Cf;  // U2a / U2b
        int ch = bb * 2048 + (n0 >> 2) + cl;
        size_t gbase = (size_t)ch * 2048 + (size_t)(m0 >> 2) * 2;
        const char* src = ls + (bb * 32 + cl) * 128;
#pragma unroll
        for (int q = 0; q < 8; q++) {
            int pq = (q * 16) ^ ((cl & 7) << 4);
            *(bf16x8*)(dstbase + gbase + q * 8) = *(const bf16x8*)(src + pq);
        }
    } else {
#pragma unroll
        for (int j = 0; j < 4; j++) {
            int col = n0 + wn * 64 + j * 16 + lm;
            float bv = bias ? (float)bias[col] : 0.f;
            float sc = (col < scale_end) ? scale : 1.f;
#pragma unroll
            for (int i = 0; i < MI; i++) {
                int row = m0 + wm * (BM / 2) + i * 16 + lg * 4;
#pragma unroll
                for (int r = 0; r < 4; r++) {
                    float v = (acc[i][j][r] + bv) * sc;
                    size_t idx = (size_t)(row + r) * ldc + col;
                    if (Cf) Cf[idx] = v;
                    if (Cb) Cb[idx] = (bf16)v;
                }
            }
        }
    }
}

// ---------------------------------------------------------------------------
// Flash attention (round-14 proven structure): QBLK=128, single K/V buffer,
// 2 barriers/kt, V pre-transposed, lazy defer-max, lane-partial lrun.
__device__ __forceinline__ int swz2(int row, int byteInRow) {
    return row * 128 + (byteInRow ^ ((row & 7) << 4));
}
__device__ __forceinline__ int swzP(int row, int byteInRow) {
    return row * 128 + (byteInRow ^ ((row & 3) << 4) ^ (((row >> 2) & 1) << 6));
}

__global__ __launch_bounds__(256) void k_attn(
    const bf16* __restrict__ Qp, const bf16* __restrict__ Kp, const bf16* __restrict__ Vt,
    int ldq, int ldk, bf16* __restrict__ Op) {
    int h = blockIdx.x & 15, b = blockIdx.x >> 4, qblk = blockIdx.y;
    int tid = threadIdx.x, w = tid >> 6, l = tid & 63, lg = l >> 4, lm = l & 15;
    int r0 = tid >> 3, ch = tid & 7;

    __shared__ __align__(16) char Ksm[64 * 128];
    __shared__ __align__(16) char Vsm[64 * 128];
    __shared__ __align__(16) char Psm[4][32 * 128];

    bf16x8 qf[2][2];
#pragma unroll
    for (int u = 0; u < 2; u++) {
        int qrow = qblk * 128 + w * 32 + u * 16 + lm;
#pragma unroll
        for (int kk = 0; kk < 2; kk++)
            qf[u][kk] = *(const bf16x8*)(Qp + (size_t)(qrow * 4 + b) * ldq + h * 64 + kk * 32 + lg * 8);
    }

    const bf16* vbase = Vt + (size_t)(b * 1024 + h * 64) * 1024;

    bf16x8 kreg[2], vreg[2];
#pragma unroll
    for (int p = 0; p < 2; p++) {
        int r = r0 + p * 32;
        kreg[p] = *(const bf16x8*)(Kp + (size_t)(r * 4 + b) * ldk + h * 64 + ch * 8);
        vreg[p] = *(const bf16x8*)(vbase + (size_t)r * 1024 + ch * 8);
    }

    f32x4 oa[2][4] = {};
    float mrun[2][4], lrun[2][4];
#pragma unroll
    for (int u = 0; u < 2; u++)
#pragma unroll
        for (int r = 0; r < 4; r++) { mrun[u][r] = -1e30f; lrun[u][r] = 0.f; }

    for (int kt = 0; kt < 16; kt++) {
        __syncthreads();
#pragma unroll
        for (int p = 0; p < 2; p++) {
            int r = r0 + p * 32;
            *(bf16x8*)(Ksm + swz2(r, ch * 16)) = kreg[p];
            *(bf16x8*)(Vsm + swz2(r, ch * 16)) = vreg[p];
        }
        if (kt < 15) {
#pragma unroll
            for (int p = 0; p < 2; p++) {
                int r = (kt + 1) * 64 + r0 + p * 32;
                kreg[p] = *(const bf16x8*)(Kp + (size_t)(r * 4 + b) * ldk + h * 64 + ch * 8);
                vreg[p] = *(const bf16x8*)(vbase + (size_t)(r0 + p * 32) * 1024 + (kt + 1) * 64 + ch * 8);
            }
        }
        __syncthreads();

        f32x4 sc[2][4] = {};
#pragma unroll
        for (int kk = 0; kk < 2; kk++)
#pragma unroll
            for (int jt = 0; jt < 4; jt++) {
                bf16x8 bk = *(const bf16x8*)(Ksm + swz2(jt * 16 + lm, kk * 64 + lg * 16));
#pragma unroll
                for (int u = 0; u < 2; u++)
                    sc[u][jt] = MFMA16(qf[u][kk], bk, sc[u][jt]);
            }

        float lmax[2][4];
        bool grow = false;
#pragma unroll
        for (int u = 0; u < 2; u++)
#pragma unroll
            for (int r = 0; r < 4; r++) {
                lmax[u][r] = fmaxf(fmaxf(sc[u][0][r], sc[u][1][r]), fmaxf(sc[u][2][r], sc[u][3][r]));
                grow = grow || (lmax[u][r] > mrun[u][r] + 8.f);
            }
        if (__any(grow)) {
#pragma unroll
            for (int u = 0; u < 2; u++)
#pragma unroll
                for (int r = 0; r < 4; r++) {
                    float m = lmax[u][r];
#pragma unroll
                    for (int d = 1; d < 16; d <<= 1) m = fmaxf(m, __shfl_xor(m, d));
                    float mn = fmaxf(mrun[u][r], m);
                    float al = __expf(mrun[u][r] - mn);
                    mrun[u][r] = mn;
                    lrun[u][r] *= al;
#pragma unroll
                    for (int ot = 0; ot < 4; ot++) oa[u][ot][r] *= al;
                }
        }
#pragma unroll
        for (int u = 0; u < 2; u++)
#pragma unroll
            for (int jt = 0; jt < 4; jt++)
#pragma unroll
                for (int r = 0; r < 4; r++) {
                    float p = __expf(sc[u][jt][r] - mrun[u][r]);
                    sc[u][jt][r] = p;
                    lrun[u][r] += p;
                }
#pragma unroll
        for (int u = 0; u < 2; u++)
#pragma unroll
            for (int jt = 0; jt < 4; jt++)
#pragma unroll
                for (int r = 0; r < 4; r++)
                    *(bf16*)(Psm[w] + swzP(u * 16 + lg * 4 + r, (jt * 16 + lm) * 2)) = (bf16)sc[u][jt][r];
        asm volatile("s_waitcnt lgkmcnt(0)" ::: "memory");
        __builtin_amdgcn_sched_barrier(0);
#pragma unroll
        for (int kk = 0; kk < 2; kk++) {
            bf16x8 pa[2];
#pragma unroll
            for (int u = 0; u < 2; u++)
                pa[u] = *(const bf16x8*)(Psm[w] + swzP(u * 16 + lm, kk * 64 + lg * 16));
#pragma unroll
            for (int ot = 0; ot < 4; ot++) {
                bf16x8 bv = *(const bf16x8*)(Vsm + swz2(ot * 16 + lm, kk * 64 + lg * 16));
#pragma unroll
                for (int u = 0; u < 2; u++)
                    oa[u][ot] = MFMA16(pa[u], bv, oa[u][ot]);
            }
        }
    }
#pragma unroll
    for (int u = 0; u < 2; u++)
#pragma unroll
        for (int r = 0; r < 4; r++) {
#pragma unroll
            for (int d = 1; d < 16; d <<= 1) lrun[u][r] += __shfl_xor(lrun[u][r], d);
            float inv = 1.f / lrun[u][r];
            int srow = qblk * 128 + w * 32 + u * 16 + lg * 4 + r;
#pragma unroll
            for (int ot = 0; ot < 4; ot++) {
                int col = h * 64 + ot * 16 + lm;
                Op[(size_t)(srow * 4 + b) * 1024 + col] = (bf16)(oa[u][ot][r] * inv);
            }
        }
}

// ---------------------------------------------------------------------------
// residual-add + LayerNorm over D=1024 (f32 math). Xalt when *flagp.
template <typename XT>
__global__ __launch_bounds__(256) void k_addln(
    const int* __restrict__ flagp,
    const XT* __restrict__ X, const XT* __restrict__ Xalt, const float* __restrict__ Yd,
    const bf16* __restrict__ g, const bf16* __restrict__ bb,
    float* __restrict__ outF, bf16* __restrict__ outB) {
    if (*flagp && Xalt) X = Xalt;
    int row = blockIdx.x * 4 + (threadIdx.x >> 6);
    int l = threadIdx.x & 63;
    const XT* xr = X + (size_t)row * 1024;
    const float* yr = Yd + (size_t)row * 1024;
    float v[16];
    float s = 0.f, s2 = 0.f;
#pragma unroll
    for (int q = 0; q < 4; q++) {
        float xa[4];
        if constexpr (sizeof(XT) == 4) {
            f32x4 a = *(const f32x4*)(xr + l * 4 + q * 256);
#pragma unroll
            for (int j = 0; j < 4; j++) xa[j] = a[j];
        } else {
            bf16x4 a = *(const bf16x4*)(xr + l * 4 + q * 256);
#pragma unroll
            for (int j = 0; j < 4; j++) xa[j] = (float)a[j];
        }
        f32x4 c = *(const f32x4*)(yr + l * 4 + q * 256);
#pragma unroll
        for (int j = 0; j < 4; j++) {
            float t = xa[j] + c[j];
            v[q * 4 + j] = t;
            s += t;
            s2 += t * t;
        }
    }
#pragma unroll
    for (int d = 1; d < 64; d <<= 1) { s += __shfl_xor(s, d); s2 += __shfl_xor(s2, d); }
    float mu = s * (1.f / 1024.f);
    float var = s2 * (1.f / 1024.f) - mu * mu;
    float rstd = rsqrtf(var + 1e-5f);
#pragma unroll
    for (int q = 0; q < 4; q++)
#pragma unroll
        for (int j = 0; j < 4; j++) {
            int col = l * 4 + q * 256 + j;
            float y = (v[q * 4 + j] - mu) * rstd * (float)g[col] + (float)bb[col];
            if (outF) outF[(size_t)row * 1024 + col] = y;
            if (outB) outB[(size_t)row * 1024 + col] = (bf16)y;
        }
}

// ---------------------------------------------------------------------------
// SRU segmented scan: 8 segments of 128 steps (affine maps), 2 phases.
__global__ __launch_bounds__(64) void k_sru_ab(
    const bf16* __restrict__ U2a, const bf16* __restrict__ v2, const bf16* __restrict__ b2,
    float* __restrict__ AB) {
    int ch = blockIdx.x * 64 + threadIdx.x;  // 0..8191
    int g = blockIdx.y;                      // 0..7
    int hh = ch & 2047;
    float vf = (float)v2[hh], bfv = (float)b2[hh];
    const bf16x8* u = (const bf16x8*)(U2a + (size_t)ch * 2048 + g * 256);
    float A = 1.f, c = 0.f;
    bf16x8 q[4];
#pragma unroll
    for (int i = 0; i < 4; i++) q[i] = u[i];
    for (int it = 0; it < 8; it++) {
#pragma unroll
        for (int j = 0; j < 4; j++) {
            int cidx = it * 4 + j;
            bf16x8 v = q[j];
            if (cidx + 4 < 32) q[j] = u[cidx + 4];
#pragma unroll
            for (int t = 0; t < 4; t++) {
                float xc = (float)v[t * 2], fp = (float)v[t * 2 + 1];
                float f = 1.f / (1.f + __expf(-(fp + vf * c + bfv)));
                A *= f;
                c = f * c + (1.f - f) * xc;
            }
        }
    }
    AB[(size_t)(g * 8192 + ch) * 2] = A;
    AB[(size_t)(g * 8192 + ch) * 2 + 1] = c;
}

__global__ __launch_bounds__(64) void k_sru_h(
    const bf16* __restrict__ U2a, const bf16* __restrict__ U2b,
    const bf16* __restrict__ v2, const bf16* __restrict__ b2,
    const float* __restrict__ AB, bf16* __restrict__ Hb) {
    int ch = blockIdx.x * 64 + threadIdx.x;
    int g = blockIdx.y;
    int b = ch >> 11, hh = ch & 2047;
    float vf = (float)v2[hh], vr = (float)v2[2048 + hh];
    float bfv = (float)b2[hh], brv = (float)b2[2048 + hh];
    float c = 0.f;
    for (int s = 0; s < g; s++) {  // wave-uniform bound
        float As = AB[(size_t)(s * 8192 + ch) * 2];
        float Bs = AB[(size_t)(s * 8192 + ch) * 2 + 1];
        c = As * c + Bs;
    }
    const bf16x8* ua = (const bf16x8*)(U2a + (size_t)ch * 2048 + g * 256);
    const bf16x8* ub = (const bf16x8*)(U2b + (size_t)ch * 2048 + g * 256);
    bf16* ho = Hb + ((size_t)(g * 128) * 4 + b) * 2048 + hh;
    bf16x8 qa[4], qb[4];
#pragma unroll
    for (int i = 0; i < 4; i++) { qa[i] = ua[i]; qb[i] = ub[i]; }
    for (int it = 0; it < 8; it++) {
#pragma unroll
        for (int j = 0; j < 4; j++) {
            int cidx = it * 4 + j;
            bf16x8 va = qa[j], vb = qb[j];
            if (cidx + 4 < 32) { qa[j] = ua[cidx + 4]; qb[j] = ub[cidx + 4]; }
#pragma unroll
            for (int t = 0; t < 4; t++) {
                float xc = (float)va[t * 2], fp = (float)va[t * 2 + 1];
                float rp = (float)vb[t * 2], xh = (float)vb[t * 2 + 1];
                float f = 1.f / (1.f + __expf(-(fp + vf * c + bfv)));
                float r = 1.f / (1.f + __expf(-(rp + vr * c + brv)));
                c = f * c + (1.f - f) * xc;
                float hv = r * c + (1.f - r) * xh;
                ho[(size_t)(cidx * 4 + t) * 8192] = (bf16)hv;
            }
        }
    }
}

// ---------------------------------------------------------------------------
extern "C" void kernel_launch(void* const* d_in, const int* in_sizes, int n_in,
                              void* d_out, int out_size, void* d_ws, size_t ws_size,
                              hipStream_t stream) {
    const size_t MB = 1u << 20;
    char* ws = (char*)d_ws;

    bf16* memB    = (bf16*)(ws + 0);
    bf16* sawinB  = (bf16*)(ws + 8 * MB);
    bf16* sawoutB = (bf16*)(ws + 14 * MB);
    bf16* cawinB  = (bf16*)(ws + 16 * MB);
    bf16* cawoutB = (bf16*)(ws + 22 * MB);
    bf16* lin2wB  = (bf16*)(ws + 24 * MB);
    char* S0 = ws + 28 * MB;
    bf16* sabinB  = (bf16*)(S0 + 0 * 8192);
    bf16* cabinB  = (bf16*)(S0 + 1 * 8192);
    bf16* saboutB = (bf16*)(S0 + 2 * 8192);
    bf16* caboutB = (bf16*)(S0 + 3 * 8192);
    bf16* lin2bB  = (bf16*)(S0 + 4 * 8192);
    bf16* sruvB   = (bf16*)(S0 + 5 * 8192);
    bf16* srubB   = (bf16*)(S0 + 6 * 8192);
    bf16* ln1gB   = (bf16*)(S0 + 7 * 8192);
    bf16* ln1bB   = (bf16*)(S0 + 8 * 8192);
    bf16* ln2gB   = (bf16*)(S0 + 9 * 8192);
    bf16* ln2bB   = (bf16*)(S0 + 10 * 8192);
    bf16* ln3gB   = (bf16*)(S0 + 11 * 8192);
    bf16* ln3bB   = (bf16*)(S0 + 12 * 8192);
    int*  flag    = (int*)(S0 + 13 * 8192);
    float* AB     = (float*)(S0 + 128 * 1024);  // 512 KB within the 1 MB region

    char* P = ws + 29 * MB;
    bf16*  t0b  = (bf16*)(P + 0);         // f32-input path only
    bf16*  qkv  = (bf16*)(P + 16 * MB);
    bf16*  qca  = qkv;
    bf16*  kvca = (bf16*)(P + 24 * MB);
    bf16*  obuf = (bf16*)(P + 40 * MB);
    bf16*  Vt   = (bf16*)(P + 56 * MB);
    float* tmp  = (float*)(P + 64 * MB);
    bf16*  t1   = (bf16*)(P + 80 * MB);
    bf16*  t2   = (bf16*)(ws + 0);        // overlays dead memB
    bf16*  wT   = (bf16*)(P + 0);         // overlays dead t0b (after ln1)
    bf16*  U2a  = (bf16*)(P + 16 * MB);   // 32MB
    bf16*  U2b  = (bf16*)(P + 48 * MB);   // 32MB
    bf16*  hb   = (bf16*)(P + 80 * MB);   // overlays dead t1
    float* tmp2 = (float*)(P + 16 * MB);  // U2a dead after scan

    const bf16* tgtA   = (const bf16*)d_in[0];
    const bf16* memA   = (const bf16*)d_in[1];
    const bf16* sawinA = (const bf16*)d_in[2];
    const bf16* sawoutA= (const bf16*)d_in[4];
    const bf16* cawinA = (const bf16*)d_in[6];
    const bf16* cawoutA= (const bf16*)d_in[8];
    const bf16* lin2wA = (const bf16*)d_in[13];

    k_detect<<<1, 256, 0, stream>>>(d_in[0], flag);
    BigSegs bg;
    {
        const void* bsrc[6] = {d_in[1], d_in[2], d_in[4], d_in[6], d_in[8], d_in[13]};
        bf16* bdst[6] = {memB, sawinB, sawoutB, cawinB, cawoutB, lin2wB};
        const int cum[7] = {0, 2048, 3584, 4096, 5632, 6144, 7168};
        for (int i = 0; i < 6; i++) { bg.src[i] = bsrc[i]; bg.dst[i] = bdst[i]; }
        for (int i = 0; i < 7; i++) bg.cum[i] = cum[i];
    }
    k_norm_big<<<7168, 256, 0, stream>>>(flag, bg);
    SmallSegs sg;
    const int srcIdx[13] = {3, 7, 5, 9, 14, 11, 12, 15, 16, 17, 18, 19, 20};
    bf16* dsts[13] = {sabinB, cabinB, saboutB, caboutB, lin2bB, sruvB, srubB,
                      ln1gB, ln1bB, ln2gB, ln2bB, ln3gB, ln3bB};
    const int n8s[13] = {384, 384, 128, 128, 128, 512, 512, 128, 128, 128, 128, 128, 128};
    for (int i = 0; i < 13; i++) { sg.src[i] = d_in[srcIdx[i]]; sg.dst[i] = dsts[i]; sg.n8[i] = n8s[i]; }
    k_norm_multi<<<13, 256, 0, stream>>>(flag, sg);

    k_cvt<<<2048, 256, 0, stream>>>(flag, d_in[0], t0b);

    // ---- self attention ----
    k_gemm<128, false><<<dim3(24, 32), 256, 0, stream>>>(flag, t0b, tgtA, 1024, sawinB, sawinA, 1024,
                                                         sabinB, nullptr, qkv, 3072, 1024, 1024, 0.125f);
    k_vtr<<<dim3(16, 16, 4), 256, 0, stream>>>(qkv + 2048, 3072, Vt);
    k_attn<<<dim3(64, 8), 256, 0, stream>>>(qkv, qkv + 1024, Vt, 3072, 3072, obuf);
    k_gemm<64, false><<<dim3(8, 64), 256, 0, stream>>>(flag, obuf, nullptr, 1024, sawoutB, sawoutA, 1024,
                                                       saboutB, tmp, nullptr, 1024, 1024, 0, 1.f);
    k_addln<bf16><<<1024, 256, 0, stream>>>(flag, t0b, tgtA, tmp, ln1gB, ln1bB, nullptr, t1);

    // ---- cross attention ----
    k_gemm<64, false><<<dim3(8, 64), 256, 0, stream>>>(flag, t1, nullptr, 1024, cawinB, cawinA, 1024,
                                                       cabinB, nullptr, qca, 1024, 1024, 1024, 0.125f);
    k_gemm<128, false><<<dim3(16, 32), 256, 0, stream>>>(flag, memB, memA, 1024,
                                                         cawinB + (size_t)1024 * 1024,
                                                         cawinA + (size_t)1024 * 1024, 1024,
                                                         cabinB + 1024, nullptr, kvca, 2048, 1024, 0, 1.f);
    k_vtr<<<dim3(16, 16, 4), 256, 0, stream>>>(kvca + 1024, 2048, Vt);
    k_attn<<<dim3(64, 8), 256, 0, stream>>>(qca, kvca, Vt, 1024, 2048, obuf);
    k_gemm<64, false><<<dim3(8, 64), 256, 0, stream>>>(flag, obuf, nullptr, 1024, cawoutB, cawoutA, 1024,
                                                       caboutB, tmp, nullptr, 1024, 1024, 0, 1.f);
    k_addln<bf16><<<1024, 256, 0, stream>>>(flag, t1, nullptr, tmp, ln2gB, ln2bB, nullptr, t2);

    // ---- SRU ----
    k_transpose<<<dim3(128, 16), 256, 0, stream>>>(flag, d_in[10], wT, 1024, 8192);
    k_gemm<128, true><<<dim3(64, 32), 256, 0, stream>>>(flag, t2, nullptr, 1024, wT, nullptr, 1024,
                                                        nullptr, (float*)U2b, U2a, 0, 1024, 0, 1.f);
    k_sru_ab<<<dim3(128, 8), 64, 0, stream>>>(U2a, sruvB, srubB, AB);
    k_sru_h<<<dim3(128, 8), 64, 0, stream>>>(U2a, U2b, sruvB, srubB, AB, hb);
    k_gemm<64, false><<<dim3(8, 64), 256, 0, stream>>>(flag, hb, nullptr, 2048, lin2wB, lin2wA, 2048,
                                                       lin2bB, tmp2, nullptr, 1024, 2048, 0, 1.f);
    k_addln<bf16><<<1024, 256, 0, stream>>>(flag, t2, nullptr, tmp2, ln3gB, ln3bB, (float*)d_out, nullptr);
}

// Round 18
// 451.257 us; speedup vs baseline: 1.0566x; 1.0144x over previous
//
#include <hip/hip_runtime.h>
#include <hip/hip_bf16.h>

typedef __bf16 bf16;
typedef bf16 bf16x8 __attribute__((ext_vector_type(8)));
typedef bf16 bf16x4 __attribute__((ext_vector_type(4)));
typedef float f32x4 __attribute__((ext_vector_type(4)));

#define MFMA16(a, b, c) __builtin_amdgcn_mfma_f32_16x16x32_bf16((a), (b), (c), 0, 0, 0)

__device__ __forceinline__ void gl_lds16(const void* g, void* l) {
    __builtin_amdgcn_global_load_lds((const __attribute__((address_space(1))) void*)g,
                                     (__attribute__((address_space(3))) void*)l, 16, 0, 0);
}

// ---------------------------------------------------------------------------
__global__ __launch_bounds__(256) void k_detect(const void* __restrict__ src, int* __restrict__ flag) {
    __shared__ int cnt;
    if (threadIdx.x == 0) cnt = 0;
    __syncthreads();
    const unsigned int* w = (const unsigned int*)src;
    int local = 0;
    for (int i = threadIdx.x; i < 4096; i += 256) {
        unsigned int e = (w[i] >> 7) & 0xFF;
        local += (e > 100 && e < 150) ? 1 : 0;
    }
    atomicAdd(&cnt, local);
    __syncthreads();
    if (threadIdx.x == 0) *flag = (cnt > 2048) ? 1 : 0;
}

struct BigSegs {
    const void* src[6];
    bf16* dst[6];
    int cum[7];
};
// copy only when inputs are f32 (flag==0); bf16 inputs consumed from d_in.
__global__ __launch_bounds__(256) void k_norm_big(const int* __restrict__ flag, BigSegs s) {
    if (*flag) return;
    int seg = 0;
#pragma unroll
    for (int t = 0; t < 5; t++) seg += (blockIdx.x >= s.cum[t + 1]) ? 1 : 0;
    int i = (blockIdx.x - s.cum[seg]) * 256 + threadIdx.x;
    const float* fs = (const float*)s.src[seg] + (size_t)i * 8;
    bf16x8 o;
#pragma unroll
    for (int j = 0; j < 8; j++) o[j] = (bf16)fs[j];
    ((bf16x8*)s.dst[seg])[i] = o;
}

struct SmallSegs {
    const void* src[13];
    bf16* dst[13];
    int n8[13];
};
__global__ __launch_bounds__(256) void k_norm_multi(const int* __restrict__ flag, SmallSegs s) {
    int seg = blockIdx.x;
    const void* sp = s.src[seg];
    bf16* dp = s.dst[seg];
    int n = s.n8[seg];
    int f = *flag;
    for (int i = threadIdx.x; i < n; i += 256) {
        if (f) {
            ((bf16x8*)dp)[i] = ((const bf16x8*)sp)[i];
        } else {
            const float* fs = (const float*)sp + (size_t)i * 8;
            bf16x8 o;
#pragma unroll
            for (int j = 0; j < 8; j++) o[j] = (bf16)fs[j];
            ((bf16x8*)dp)[i] = o;
        }
    }
}

// tgt(f32) -> bf16 t0b; no-op when inputs are bf16.
__global__ __launch_bounds__(256) void k_cvt(const int* __restrict__ flag, const void* __restrict__ in,
                                             bf16* __restrict__ outb) {
    if (*flag) return;
    size_t i = (size_t)blockIdx.x * 256 + threadIdx.x;
    f32x4 a = ((const f32x4*)in)[i * 2];
    f32x4 b = ((const f32x4*)in)[i * 2 + 1];
    bf16x8 v;
#pragma unroll
    for (int j = 0; j < 4; j++) { v[j] = (bf16)a[j]; v[4 + j] = (bf16)b[j]; }
    ((bf16x8*)outb)[i] = v;
}

// ---------------------------------------------------------------------------
// transpose+permute: sru_w (1024,8192) -> wT' (8192,1024) with row n'=h*4+j
__global__ __launch_bounds__(256) void k_transpose(const int* __restrict__ flag, const void* __restrict__ in,
                                                   bf16* __restrict__ out, int R, int C) {
    __shared__ __align__(16) bf16 t[64][72];
    int tid = threadIdx.x;
    int c0 = blockIdx.x * 64, r0 = blockIdx.y * 64;
#pragma unroll
    for (int i = 0; i < 2; i++) {
        int idx = tid + i * 256;
        int r = idx >> 3, ch = idx & 7;
        size_t base = (size_t)(r0 + r) * C + c0 + ch * 8;
        bf16x8 v;
        if (*flag) {
            v = *(const bf16x8*)((const bf16*)in + base);
        } else {
            const float* f = (const float*)in + base;
            f32x4 x = *(const f32x4*)f, y = *(const f32x4*)(f + 4);
#pragma unroll
            for (int j = 0; j < 4; j++) { v[j] = (bf16)x[j]; v[4 + j] = (bf16)y[j]; }
        }
        *(bf16x8*)&t[r][ch * 8] = v;
    }
    __syncthreads();
    int nbase = c0 & 2047, joff = c0 >> 11;
#pragma unroll
    for (int i = 0; i < 2; i++) {
        int idx = tid + i * 256;
        int cr = idx >> 3, ch = idx & 7;
        bf16x8 v;
#pragma unroll
        for (int j = 0; j < 8; j++) v[j] = t[ch * 8 + j][cr];
        int np = (nbase + cr) * 4 + joff;
        *(bf16x8*)(out + (size_t)np * R + r0 + ch * 8) = v;
    }
}

// ---------------------------------------------------------------------------
// V pre-transpose: in rows m=s*4+b, 64 cols -> Vt[b][n][s] ([4][1024][1024])
__global__ __launch_bounds__(256) void k_vtr(const bf16* __restrict__ in, int ldv, bf16* __restrict__ out) {
    int nt = blockIdx.x, st = blockIdx.y, b = blockIdx.z;
    __shared__ __align__(16) bf16 t[64][72];
    int tid = threadIdx.x;
#pragma unroll
    for (int i = 0; i < 2; i++) {
        int idx = tid + i * 256;
        int r = idx >> 3, ch = idx & 7;
        bf16x8 v = *(const bf16x8*)(in + (size_t)((st * 64 + r) * 4 + b) * ldv + nt * 64 + ch * 8);
        *(bf16x8*)&t[r][ch * 8] = v;
    }
    __syncthreads();
#pragma unroll
    for (int i = 0; i < 2; i++) {
        int idx = tid + i * 256;
        int dr = idx >> 3, ch = idx & 7;
        bf16x8 v;
#pragma unroll
        for (int j = 0; j < 8; j++) v[j] = t[ch * 8 + j][dr];
        *(bf16x8*)(out + (size_t)(b * 1024 + nt * 64 + dr) * 1024 + st * 64 + ch * 8) = v;
    }
}

// ---------------------------------------------------------------------------
// GEMM (bf16 A): C = A @ W^T (+bias)(*scale). BMx128 tile, BK=64, 4 waves.
// Aalt/Walt: raw d_in pointers selected when *flagp (bf16 inputs, zero-copy).
// USCAT epilogue: LDS-staged 128B-contiguous runs into U2a/U2b (proven 94.8us).
__device__ __forceinline__ int swzB(int r, int byteInRow) {
    return r * 128 + (byteInRow ^ ((r & 7) << 4));
}

template <int BM, bool USCAT>
__global__ __launch_bounds__(256) void k_gemm(
    const int* __restrict__ flagp,
    const bf16* __restrict__ A, const bf16* __restrict__ Aalt, int lda,
    const bf16* __restrict__ W, const bf16* __restrict__ Walt, int ldw,
    const bf16* __restrict__ bias,
    float* __restrict__ Cf, bf16* __restrict__ Cb, int ldc,
    int K, int scale_end, float scale) {
    constexpr int MI = BM / 32;
    __shared__ __align__(16) char Asm[BM * 128];
    __shared__ __align__(16) char Bsm[128 * 128];
    if (*flagp) {
        if (Aalt) A = Aalt;
        if (Walt) W = Walt;
    }
    int tid = threadIdx.x, w = tid >> 6, l = tid & 63, lg = l >> 4, lm = l & 15;
    int wm = w >> 1, wn = w & 1;
    int m0 = blockIdx.y * BM, n0 = blockIdx.x * 128;

    f32x4 acc[MI][4] = {};

    for (int k0 = 0; k0 < K; k0 += 64) {
#pragma unroll
        for (int i = 0; i < BM / 32; i++) {
            int r = i * 32 + w * 8 + (l >> 3);
            int gs = (l & 7) ^ (r & 7);
            gl_lds16(A + (size_t)(m0 + r) * lda + k0 + gs * 8,
                     Asm + (i * 32 + w * 8) * 128);
        }
#pragma unroll
        for (int i = 0; i < 4; i++) {
            int r = i * 32 + w * 8 + (l >> 3);
            int gs = (l & 7) ^ (r & 7);
            gl_lds16(W + (size_t)(n0 + r) * ldw + k0 + gs * 8,
                     Bsm + (i * 32 + w * 8) * 128);
        }
        __syncthreads();
#pragma unroll
        for (int kh = 0; kh < 2; kh++) {
            bf16x8 af[MI], bfr[4];
#pragma unroll
            for (int i = 0; i < MI; i++)
                af[i] = *(const bf16x8*)(Asm + swzB(wm * (BM / 2) + i * 16 + lm, kh * 64 + lg * 16));
#pragma unroll
            for (int j = 0; j < 4; j++)
                bfr[j] = *(const bf16x8*)(Bsm + swzB(wn * 64 + j * 16 + lm, kh * 64 + lg * 16));
#pragma unroll
            for (int i = 0; i < MI; i++)
#pragma unroll
                for (int j = 0; j < 4; j++)
                    acc[i][j] = MFMA16(af[i], bfr[j], acc[i][j]);
        }
        __syncthreads();
    }
    if constexpr (USCAT) {
        bf16* lsA = (bf16*)Asm;  // 16 KB (BM=128)
        bf16* lsB = (bf16*)Bsm;  // 16 KB
#pragma unroll
        for (int j = 0; j < 4; j++) {
            int cl = wn * 16 + j * 4 + (lm >> 2);
            int g = lm & 3;
            bf16* ls = (g < 2) ? lsA : lsB;
            int g01 = g & 1;
#pragma unroll
            for (int i = 0; i < MI; i++) {
                int slb = wm * 16 + i * 4 + lg;
                int boff = (slb * 2 + g01) * 2;
                int swz = boff ^ ((cl & 7) << 4);
#pragma unroll
                for (int r = 0; r < 4; r++) {
                    float v = acc[i][j][r];
                    *(bf16*)((char*)ls + (r * 32 + cl) * 128 + swz) = (bf16)v;
                }
            }
        }
        __syncthreads();
        int buf = tid >> 7, bb = (tid >> 5) & 3, cl = tid & 31;
        const char* ls = (buf == 0) ? (const char*)lsA : (const char*)lsB;
        bf16* dstbase = (buf == 0) ? Cb : (bf16*)Cf;  // U2a / U2b
        int ch = bb * 2048 + (n0 >> 2) + cl;
        size_t gbase = (size_t)ch * 2048 + (size_t)(m0 >> 2) * 2;
        const char* src = ls + (bb * 32 + cl) * 128;
#pragma unroll
        for (int q = 0; q < 8; q++) {
            int pq = (q * 16) ^ ((cl & 7) << 4);
            *(bf16x8*)(dstbase + gbase + q * 8) = *(const bf16x8*)(src + pq);
        }
    } else {
#pragma unroll
        for (int j = 0; j < 4; j++) {
            int col = n0 + wn * 64 + j * 16 + lm;
            float bv = bias ? (float)bias[col] : 0.f;
            float sc = (col < scale_end) ? scale : 1.f;
#pragma unroll
            for (int i = 0; i < MI; i++) {
                int row = m0 + wm * (BM / 2) + i * 16 + lg * 4;
#pragma unroll
                for (int r = 0; r < 4; r++) {
                    float v = (acc[i][j][r] + bv) * sc;
                    size_t idx = (size_t)(row + r) * ldc + col;
                    if (Cf) Cf[idx] = v;
                    if (Cb) Cb[idx] = (bf16)v;
                }
            }
        }
    }
}

// ---------------------------------------------------------------------------
// Flash attention (proven structure): QBLK=128, single K/V buffer,
// 2 barriers/kt, V pre-transposed, lazy defer-max, lane-partial lrun.
__device__ __forceinline__ int swz2(int row, int byteInRow) {
    return row * 128 + (byteInRow ^ ((row & 7) << 4));
}
__device__ __forceinline__ int swzP(int row, int byteInRow) {
    return row * 128 + (byteInRow ^ ((row & 3) << 4) ^ (((row >> 2) & 1) << 6));
}

__global__ __launch_bounds__(256) void k_attn(
    const bf16* __restrict__ Qp, const bf16* __restrict__ Kp, const bf16* __restrict__ Vt,
    int ldq, int ldk, bf16* __restrict__ Op) {
    int h = blockIdx.x & 15, b = blockIdx.x >> 4, qblk = blockIdx.y;
    int tid = threadIdx.x, w = tid >> 6, l = tid & 63, lg = l >> 4, lm = l & 15;
    int r0 = tid >> 3, ch = tid & 7;

    __shared__ __align__(16) char Ksm[64 * 128];
    __shared__ __align__(16) char Vsm[64 * 128];
    __shared__ __align__(16) char Psm[4][32 * 128];

    bf16x8 qf[2][2];
#pragma unroll
    for (int u = 0; u < 2; u++) {
        int qrow = qblk * 128 + w * 32 + u * 16 + lm;
#pragma unroll
        for (int kk = 0; kk < 2; kk++)
            qf[u][kk] = *(const bf16x8*)(Qp + (size_t)(qrow * 4 + b) * ldq + h * 64 + kk * 32 + lg * 8);
    }

    const bf16* vbase = Vt + (size_t)(b * 1024 + h * 64) * 1024;

    bf16x8 kreg[2], vreg[2];
#pragma unroll
    for (int p = 0; p < 2; p++) {
        int r = r0 + p * 32;
        kreg[p] = *(const bf16x8*)(Kp + (size_t)(r * 4 + b) * ldk + h * 64 + ch * 8);
        vreg[p] = *(const bf16x8*)(vbase + (size_t)r * 1024 + ch * 8);
    }

    f32x4 oa[2][4] = {};
    float mrun[2][4], lrun[2][4];
#pragma unroll
    for (int u = 0; u < 2; u++)
#pragma unroll
        for (int r = 0; r < 4; r++) { mrun[u][r] = -1e30f; lrun[u][r] = 0.f; }

    for (int kt = 0; kt < 16; kt++) {
        __syncthreads();
#pragma unroll
        for (int p = 0; p < 2; p++) {
            int r = r0 + p * 32;
            *(bf16x8*)(Ksm + swz2(r, ch * 16)) = kreg[p];
            *(bf16x8*)(Vsm + swz2(r, ch * 16)) = vreg[p];
        }
        if (kt < 15) {
#pragma unroll
            for (int p = 0; p < 2; p++) {
                int r = (kt + 1) * 64 + r0 + p * 32;
                kreg[p] = *(const bf16x8*)(Kp + (size_t)(r * 4 + b) * ldk + h * 64 + ch * 8);
                vreg[p] = *(const bf16x8*)(vbase + (size_t)(r0 + p * 32) * 1024 + (kt + 1) * 64 + ch * 8);
            }
        }
        __syncthreads();

        f32x4 sc[2][4] = {};
#pragma unroll
        for (int kk = 0; kk < 2; kk++)
#pragma unroll
            for (int jt = 0; jt < 4; jt++) {
                bf16x8 bk = *(const bf16x8*)(Ksm + swz2(jt * 16 + lm, kk * 64 + lg * 16));
#pragma unroll
                for (int u = 0; u < 2; u++)
                    sc[u][jt] = MFMA16(qf[u][kk], bk, sc[u][jt]);
            }

        float lmax[2][4];
        bool grow = false;
#pragma unroll
        for (int u = 0; u < 2; u++)
#pragma unroll
            for (int r = 0; r < 4; r++) {
                lmax[u][r] = fmaxf(fmaxf(sc[u][0][r], sc[u][1][r]), fmaxf(sc[u][2][r], sc[u][3][r]));
                grow = grow || (lmax[u][r] > mrun[u][r] + 8.f);
            }
        if (__any(grow)) {
#pragma unroll
            for (int u = 0; u < 2; u++)
#pragma unroll
                for (int r = 0; r < 4; r++) {
                    float m = lmax[u][r];
#pragma unroll
                    for (int d = 1; d < 16; d <<= 1) m = fmaxf(m, __shfl_xor(m, d));
                    float mn = fmaxf(mrun[u][r], m);
                    float al = __expf(mrun[u][r] - mn);
                    mrun[u][r] = mn;
                    lrun[u][r] *= al;
#pragma unroll
                    for (int ot = 0; ot < 4; ot++) oa[u][ot][r] *= al;
                }
        }
#pragma unroll
        for (int u = 0; u < 2; u++)
#pragma unroll
            for (int jt = 0; jt < 4; jt++)
#pragma unroll
                for (int r = 0; r < 4; r++) {
                    float p = __expf(sc[u][jt][r] - mrun[u][r]);
                    sc[u][jt][r] = p;
                    lrun[u][r] += p;
                }
#pragma unroll
        for (int u = 0; u < 2; u++)
#pragma unroll
            for (int jt = 0; jt < 4; jt++)
#pragma unroll
                for (int r = 0; r < 4; r++)
                    *(bf16*)(Psm[w] + swzP(u * 16 + lg * 4 + r, (jt * 16 + lm) * 2)) = (bf16)sc[u][jt][r];
        asm volatile("s_waitcnt lgkmcnt(0)" ::: "memory");
        __builtin_amdgcn_sched_barrier(0);
#pragma unroll
        for (int kk = 0; kk < 2; kk++) {
            bf16x8 pa[2];
#pragma unroll
            for (int u = 0; u < 2; u++)
                pa[u] = *(const bf16x8*)(Psm[w] + swzP(u * 16 + lm, kk * 64 + lg * 16));
#pragma unroll
            for (int ot = 0; ot < 4; ot++) {
                bf16x8 bv = *(const bf16x8*)(Vsm + swz2(ot * 16 + lm, kk * 64 + lg * 16));
#pragma unroll
                for (int u = 0; u < 2; u++)
                    oa[u][ot] = MFMA16(pa[u], bv, oa[u][ot]);
            }
        }
    }
#pragma unroll
    for (int u = 0; u < 2; u++)
#pragma unroll
        for (int r = 0; r < 4; r++) {
#pragma unroll
            for (int d = 1; d < 16; d <<= 1) lrun[u][r] += __shfl_xor(lrun[u][r], d);
            float inv = 1.f / lrun[u][r];
            int srow = qblk * 128 + w * 32 + u * 16 + lg * 4 + r;
#pragma unroll
            for (int ot = 0; ot < 4; ot++) {
                int col = h * 64 + ot * 16 + lm;
                Op[(size_t)(srow * 4 + b) * 1024 + col] = (bf16)(oa[u][ot][r] * inv);
            }
        }
}

// ---------------------------------------------------------------------------
// residual-add + LayerNorm over D=1024 (f32 math). X and Yd both bf16.
// Xalt: raw d_in pointer used when *flagp (zero-copy residual).
__global__ __launch_bounds__(256) void k_addln(
    const int* __restrict__ flagp,
    const bf16* __restrict__ X, const bf16* __restrict__ Xalt, const bf16* __restrict__ Yd,
    const bf16* __restrict__ g, const bf16* __restrict__ bb,
    float* __restrict__ outF, bf16* __restrict__ outB) {
    if (*flagp && Xalt) X = Xalt;
    int row = blockIdx.x * 4 + (threadIdx.x >> 6);
    int l = threadIdx.x & 63;
    const bf16* xr = X + (size_t)row * 1024;
    const bf16* yr = Yd + (size_t)row * 1024;
    float v[16];
    float s = 0.f, s2 = 0.f;
#pragma unroll
    for (int q = 0; q < 4; q++) {
        bf16x4 a = *(const bf16x4*)(xr + l * 4 + q * 256);
        bf16x4 c = *(const bf16x4*)(yr + l * 4 + q * 256);
#pragma unroll
        for (int j = 0; j < 4; j++) {
            float t = (float)a[j] + (float)c[j];
            v[q * 4 + j] = t;
            s += t;
            s2 += t * t;
        }
    }
#pragma unroll
    for (int d = 1; d < 64; d <<= 1) { s += __shfl_xor(s, d); s2 += __shfl_xor(s2, d); }
    float mu = s * (1.f / 1024.f);
    float var = s2 * (1.f / 1024.f) - mu * mu;
    float rstd = rsqrtf(var + 1e-5f);
#pragma unroll
    for (int q = 0; q < 4; q++)
#pragma unroll
        for (int j = 0; j < 4; j++) {
            int col = l * 4 + q * 256 + j;
            float y = (v[q * 4 + j] - mu) * rstd * (float)g[col] + (float)bb[col];
            if (outF) outF[(size_t)row * 1024 + col] = y;
            if (outB) outB[(size_t)row * 1024 + col] = (bf16)y;
        }
}

// ---------------------------------------------------------------------------
// SRU segmented scan: 8 segments of 128 steps (affine maps), 2 phases.
__global__ __launch_bounds__(64) void k_sru_ab(
    const bf16* __restrict__ U2a, const bf16* __restrict__ v2, const bf16* __restrict__ b2,
    float* __restrict__ AB) {
    int ch = blockIdx.x * 64 + threadIdx.x;  // 0..8191
    int g = blockIdx.y;                      // 0..7
    int hh = ch & 2047;
    float vf = (float)v2[hh], bfv = (float)b2[hh];
    const bf16x8* u = (const bf16x8*)(U2a + (size_t)ch * 2048 + g * 256);
    float A = 1.f, c = 0.f;
    bf16x8 q[4];
#pragma unroll
    for (int i = 0; i < 4; i++) q[i] = u[i];
    for (int it = 0; it < 8; it++) {
#pragma unroll
        for (int j = 0; j < 4; j++) {
            int cidx = it * 4 + j;
            bf16x8 v = q[j];
            if (cidx + 4 < 32) q[j] = u[cidx + 4];
#pragma unroll
            for (int t = 0; t < 4; t++) {
                float xc = (float)v[t * 2], fp = (float)v[t * 2 + 1];
                float f = 1.f / (1.f + __expf(-(fp + vf * c + bfv)));
                A *= f;
                c = f * c + (1.f - f) * xc;
            }
        }
    }
    AB[(size_t)(g * 8192 + ch) * 2] = A;
    AB[(size_t)(g * 8192 + ch) * 2 + 1] = c;
}

__global__ __launch_bounds__(64) void k_sru_h(
    const bf16* __restrict__ U2a, const bf16* __restrict__ U2b,
    const bf16* __restrict__ v2, const bf16* __restrict__ b2,
    const float* __restrict__ AB, bf16* __restrict__ Hb) {
    int ch = blockIdx.x * 64 + threadIdx.x;
    int g = blockIdx.y;
    int b = ch >> 11, hh = ch & 2047;
    float vf = (float)v2[hh], vr = (float)v2[2048 + hh];
    float bfv = (float)b2[hh], brv = (float)b2[2048 + hh];
    float c = 0.f;
    for (int s = 0; s < g; s++) {  // wave-uniform bound
        float As = AB[(size_t)(s * 8192 + ch) * 2];
        float Bs = AB[(size_t)(s * 8192 + ch) * 2 + 1];
        c = As * c + Bs;
    }
    const bf16x8* ua = (const bf16x8*)(U2a + (size_t)ch * 2048 + g * 256);
    const bf16x8* ub = (const bf16x8*)(U2b + (size_t)ch * 2048 + g * 256);
    bf16* ho = Hb + ((size_t)(g * 128) * 4 + b) * 2048 + hh;
    bf16x8 qa[4], qb[4];
#pragma unroll
    for (int i = 0; i < 4; i++) { qa[i] = ua[i]; qb[i] = ub[i]; }
    for (int it = 0; it < 8; it++) {
#pragma unroll
        for (int j = 0; j < 4; j++) {
            int cidx = it * 4 + j;
            bf16x8 va = qa[j], vb = qb[j];
            if (cidx + 4 < 32) { qa[j] = ua[cidx + 4]; qb[j] = ub[cidx + 4]; }
#pragma unroll
            for (int t = 0; t < 4; t++) {
                float xc = (float)va[t * 2], fp = (float)va[t * 2 + 1];
                float rp = (float)vb[t * 2], xh = (float)vb[t * 2 + 1];
                float f = 1.f / (1.f + __expf(-(fp + vf * c + bfv)));
                float r = 1.f / (1.f + __expf(-(rp + vr * c + brv)));
                c = f * c + (1.f - f) * xc;
                float hv = r * c + (1.f - r) * xh;
                ho[(size_t)(cidx * 4 + t) * 8192] = (bf16)hv;
            }
        }
    }
}

// ---------------------------------------------------------------------------
extern "C" void kernel_launch(void* const* d_in, const int* in_sizes, int n_in,
                              void* d_out, int out_size, void* d_ws, size_t ws_size,
                              hipStream_t stream) {
    const size_t MB = 1u << 20;
    char* ws = (char*)d_ws;

    bf16* memB    = (bf16*)(ws + 0);
    bf16* sawinB  = (bf16*)(ws + 8 * MB);
    bf16* sawoutB = (bf16*)(ws + 14 * MB);
    bf16* cawinB  = (bf16*)(ws + 16 * MB);
    bf16* cawoutB = (bf16*)(ws + 22 * MB);
    bf16* lin2wB  = (bf16*)(ws + 24 * MB);
    char* S0 = ws + 28 * MB;
    bf16* sabinB  = (bf16*)(S0 + 0 * 8192);
    bf16* cabinB  = (bf16*)(S0 + 1 * 8192);
    bf16* saboutB = (bf16*)(S0 + 2 * 8192);
    bf16* caboutB = (bf16*)(S0 + 3 * 8192);
    bf16* lin2bB  = (bf16*)(S0 + 4 * 8192);
    bf16* sruvB   = (bf16*)(S0 + 5 * 8192);
    bf16* srubB   = (bf16*)(S0 + 6 * 8192);
    bf16* ln1gB   = (bf16*)(S0 + 7 * 8192);
    bf16* ln1bB   = (bf16*)(S0 + 8 * 8192);
    bf16* ln2gB   = (bf16*)(S0 + 9 * 8192);
    bf16* ln2bB   = (bf16*)(S0 + 10 * 8192);
    bf16* ln3gB   = (bf16*)(S0 + 11 * 8192);
    bf16* ln3bB   = (bf16*)(S0 + 12 * 8192);
    int*  flag    = (int*)(S0 + 13 * 8192);
    float* AB     = (float*)(S0 + 128 * 1024);  // 512 KB within the 1 MB region

    char* P = ws + 29 * MB;
    bf16*  t0b  = (bf16*)(P + 0);         // f32-input path only
    bf16*  qkv  = (bf16*)(P + 16 * MB);
    bf16*  qca  = qkv;
    bf16*  kvca = (bf16*)(P + 24 * MB);
    bf16*  obuf = (bf16*)(P + 40 * MB);
    bf16*  Vt   = (bf16*)(P + 56 * MB);
    bf16*  tmpb = (bf16*)(P + 64 * MB);   // 4096x1024 bf16 out-proj results
    bf16*  t1   = (bf16*)(P + 80 * MB);
    bf16*  t2   = (bf16*)(ws + 0);        // overlays dead memB
    bf16*  wT   = (bf16*)(P + 0);         // overlays dead t0b (after ln1)
    bf16*  U2a  = (bf16*)(P + 16 * MB);   // 32MB
    bf16*  U2b  = (bf16*)(P + 48 * MB);   // 32MB
    bf16*  hb   = (bf16*)(P + 80 * MB);   // overlays dead t1
    bf16*  tmp2b= (bf16*)(P + 16 * MB);   // U2a dead after scan

    const bf16* tgtA   = (const bf16*)d_in[0];
    const bf16* memA   = (const bf16*)d_in[1];
    const bf16* sawinA = (const bf16*)d_in[2];
    const bf16* sawoutA= (const bf16*)d_in[4];
    const bf16* cawinA = (const bf16*)d_in[6];
    const bf16* cawoutA= (const bf16*)d_in[8];
    const bf16* lin2wA = (const bf16*)d_in[13];

    k_detect<<<1, 256, 0, stream>>>(d_in[0], flag);
    BigSegs bg;
    {
        const void* bsrc[6] = {d_in[1], d_in[2], d_in[4], d_in[6], d_in[8], d_in[13]};
        bf16* bdst[6] = {memB, sawinB, sawoutB, cawinB, cawoutB, lin2wB};
        const int cum[7] = {0, 2048, 3584, 4096, 5632, 6144, 7168};
        for (int i = 0; i < 6; i++) { bg.src[i] = bsrc[i]; bg.dst[i] = bdst[i]; }
        for (int i = 0; i < 7; i++) bg.cum[i] = cum[i];
    }
    k_norm_big<<<7168, 256, 0, stream>>>(flag, bg);
    SmallSegs sg;
    const int srcIdx[13] = {3, 7, 5, 9, 14, 11, 12, 15, 16, 17, 18, 19, 20};
    bf16* dsts[13] = {sabinB, cabinB, saboutB, caboutB, lin2bB, sruvB, srubB,
                      ln1gB, ln1bB, ln2gB, ln2bB, ln3gB, ln3bB};
    const int n8s[13] = {384, 384, 128, 128, 128, 512, 512, 128, 128, 128, 128, 128, 128};
    for (int i = 0; i < 13; i++) { sg.src[i] = d_in[srcIdx[i]]; sg.dst[i] = dsts[i]; sg.n8[i] = n8s[i]; }
    k_norm_multi<<<13, 256, 0, stream>>>(flag, sg);

    k_cvt<<<2048, 256, 0, stream>>>(flag, d_in[0], t0b);

    // ---- self attention ----
    k_gemm<128, false><<<dim3(24, 32), 256, 0, stream>>>(flag, t0b, tgtA, 1024, sawinB, sawinA, 1024,
                                                         sabinB, nullptr, qkv, 3072, 1024, 1024, 0.125f);
    k_vtr<<<dim3(16, 16, 4), 256, 0, stream>>>(qkv + 2048, 3072, Vt);
    k_attn<<<dim3(64, 8), 256, 0, stream>>>(qkv, qkv + 1024, Vt, 3072, 3072, obuf);
    k_gemm<64, false><<<dim3(8, 64), 256, 0, stream>>>(flag, obuf, nullptr, 1024, sawoutB, sawoutA, 1024,
                                                       saboutB, nullptr, tmpb, 1024, 1024, 0, 1.f);
    k_addln<<<1024, 256, 0, stream>>>(flag, t0b, tgtA, tmpb, ln1gB, ln1bB, nullptr, t1);

    // ---- cross attention ----
    k_gemm<64, false><<<dim3(8, 64), 256, 0, stream>>>(flag, t1, nullptr, 1024, cawinB, cawinA, 1024,
                                                       cabinB, nullptr, qca, 1024, 1024, 1024, 0.125f);
    k_gemm<128, false><<<dim3(16, 32), 256, 0, stream>>>(flag, memB, memA, 1024,
                                                         cawinB + (size_t)1024 * 1024,
                                                         cawinA + (size_t)1024 * 1024, 1024,
                                                         cabinB + 1024, nullptr, kvca, 2048, 1024, 0, 1.f);
    k_vtr<<<dim3(16, 16, 4), 256, 0, stream>>>(kvca + 1024, 2048, Vt);
    k_attn<<<dim3(64, 8), 256, 0, stream>>>(qca, kvca, Vt, 1024, 2048, obuf);
    k_gemm<64, false><<<dim3(8, 64), 256, 0, stream>>>(flag, obuf, nullptr, 1024, cawoutB, cawoutA, 1024,
                                                       caboutB, nullptr, tmpb, 1024, 1024, 0, 1.f);
    k_addln<<<1024, 256, 0, stream>>>(flag, t1, nullptr, tmpb, ln2gB, ln2bB, nullptr, t2);

    // ---- SRU ----
    k_transpose<<<dim3(128, 16), 256, 0, stream>>>(flag, d_in[10], wT, 1024, 8192);
    k_gemm<128, true><<<dim3(64, 32), 256, 0, stream>>>(flag, t2, nullptr, 1024, wT, nullptr, 1024,
                                                        nullptr, (float*)U2b, U2a, 0, 1024, 0, 1.f);
    k_sru_ab<<<dim3(128, 8), 64, 0, stream>>>(U2a, sruvB, srubB, AB);
    k_sru_h<<<dim3(128, 8), 64, 0, stream>>>(U2a, U2b, sruvB, srubB, AB, hb);
    k_gemm<64, false><<<dim3(8, 64), 256, 0, stream>>>(flag, hb, nullptr, 2048, lin2wB, lin2wA, 2048,
                                                       lin2bB, nullptr, tmp2b, 1024, 2048, 0, 1.f);
    k_addln<<<1024, 256, 0, stream>>>(flag, t2, nullptr, tmp2b, ln3gB, ln3bB, (float*)d_out, nullptr);
}